// Round 2
// baseline (1630.844 us; speedup 1.0000x reference)
//
#include <hip/hip_runtime.h>
#include <math.h>

#define NB 4
#define NM 32
#define CTOT 282
#define EPSV 1e-3f

// per-level constants: channels, spatial size, channel offset, per-batch freq offset
__constant__ int g_cL[5]   = {192,48,24,12,6};
__constant__ int g_hL[5]   = {2,4,8,16,32};
__constant__ int g_coff[5] = {0,192,240,264,276};
__constant__ int g_zo[5]   = {0,768,1536,3072,6144};

// workspace layout (float offsets)
#define N_LA     (NM*CTOT*CTOT)            /* 2544768 */
#define OFF_LA   0
#define OFF_ZRE  (OFF_LA + N_LA)
#define OFF_ZIM  (OFF_ZRE + NB*12288)
#define OFF_WRE  (OFF_ZIM + NB*12288)
#define OFF_WIM  (OFF_WRE + NB*12288)
#define OFF_LAM  (OFF_WIM + NB*12288)      /* NM*1024 */
#define OFF_VRE  (OFF_LAM + NM*1024)
#define OFF_VIM  (OFF_VRE + NB*NM*12288)
#define OFF_SZZ  (OFF_VIM + NB*NM*12288)
#define OFF_SZW  (OFF_SZZ + NB*NM*NM)
#define OFF_SWW  (OFF_SZW + NB*NM)

__device__ __forceinline__ int level_of(int c){
  return (c < 192) ? 0 : (c < 240) ? 1 : (c < 264) ? 2 : (c < 276) ? 3 : 4;
}

// La[m,c,d] = L[m,c,d] - L[m,d,c];  LamIm[m,k] = lam[m,k] - lam[m,-k]
__global__ void k_prep(const float* __restrict__ L, const float* __restrict__ lam,
                       float* __restrict__ ws){
  int idx = blockIdx.x*blockDim.x + threadIdx.x;
  if (idx < N_LA){
    int m = idx / (CTOT*CTOT);
    int r = idx - m*(CTOT*CTOT);
    int c = r / CTOT, d = r - (r/CTOT)*CTOT;
    ws[OFF_LA + idx] = L[idx] - L[(m*CTOT + d)*CTOT + c];
  } else if (idx < N_LA + NM*1024){
    int i = idx - N_LA;
    int m = i >> 10, k = i & 1023;
    int ky = k >> 5, kx = k & 31;
    int nk = (((32-ky)&31) << 5) | ((32-kx)&31);
    ws[OFF_LAM + i] = lam[(m<<10)+k] - lam[(m<<10)+nk];
  }
}

// small separable 2D DFTs of z levels (unscaled) and w levels (scaled 1/h)
__global__ void k_dft(const float* z0,const float* z1,const float* z2,const float* z3,const float* z4,
                      const float* w0,const float* w1,const float* w2,const float* w3,const float* w4,
                      float* __restrict__ ws){
  __shared__ float sIn[1024], s1r[1024], s1i[1024], lc[32], lsn[32];
  int t = threadIdx.x;
  int bid = blockIdx.x;
  int which = bid / (NB*CTOT);
  int rem = bid % (NB*CTOT);
  int b = rem / CTOT, cg = rem % CTOT;
  int l = level_of(cg);
  int cl = cg - g_coff[l];
  int h = g_hL[l], n = h*h;
  const float* src;
  switch (which*5 + l){
    case 0: src=z0; break; case 1: src=z1; break; case 2: src=z2; break;
    case 3: src=z3; break; case 4: src=z4; break;
    case 5: src=w0; break; case 6: src=w1; break; case 7: src=w2; break;
    case 8: src=w3; break; default: src=w4; break;
  }
  for (int i=t;i<n;i+=64) sIn[i] = src[(b*g_cL[l] + cl)*n + i];
  for (int j=t;j<h;j+=64){
    float ang = -6.2831853071795864f * (float)j / (float)h;
    lc[j] = cosf(ang); lsn[j] = sinf(ang);
  }
  __syncthreads();
  // rows: out1[y,kx] = sum_x in[y,x] * e^{-2pi i kx x / h}
  for (int p=t;p<n;p+=64){
    int y=p/h, kx=p-y*h;
    float re=0.f, im=0.f;
    for (int x=0;x<h;x++){
      int id = (kx*x)%h;
      float v = sIn[y*h+x];
      re += v*lc[id]; im += v*lsn[id];
    }
    s1r[p]=re; s1i[p]=im;
  }
  __syncthreads();
  float scale = which ? 1.0f/(float)h : 1.0f;   // W pre-scaled by 1/h for Parseval
  float* outR = ws + (which?OFF_WRE:OFF_ZRE) + b*12288 + g_zo[l] + cl*n;
  float* outI = ws + (which?OFF_WIM:OFF_ZIM) + b*12288 + g_zo[l] + cl*n;
  for (int p=t;p<n;p+=64){
    int ky=p/h, kx=p-(p/h)*h;
    float re=0.f, im=0.f;
    for (int y=0;y<h;y++){
      int id=(ky*y)%h;
      float c=lc[id], s=lsn[id];
      float ar=s1r[y*h+kx], ai=s1i[y*h+kx];
      re += ar*c - ai*s;
      im += ar*s + ai*c;
    }
    outR[p]=re*scale; outI[p]=im*scale;
  }
}

__global__ void k_sww(const float* w0,const float* w1,const float* w2,const float* w3,const float* w4,
                      float* __restrict__ ws){
  __shared__ float red[256];
  int b = blockIdx.x, t = threadIdx.x;
  const float* ptr[5] = {w0,w1,w2,w3,w4};
  float s = 0.f;
  for (int l=0;l<5;l++){
    int sz = g_cL[l]*g_hL[l]*g_hL[l];
    const float* p = ptr[l] + b*sz;
    for (int i=t;i<sz;i+=256){ float v=p[i]; s += v*v; }
  }
  red[t]=s; __syncthreads();
  for (int o=128;o>0;o>>=1){ if (t<o) red[t]+=red[t+o]; __syncthreads(); }
  if (t==0) ws[OFF_SWW + b] = red[0];
}

// hot kernel: per (b,m,d) block -> compact partials P_l in LDS, then alias-fold
__global__ void __launch_bounds__(256) k_fold(float* __restrict__ ws){
  __shared__ float pre[340], pim[340], sla4[6], redR[256], redI[256];
  int t = threadIdx.x;
  int bid = blockIdx.x;
  int dd = bid % CTOT;
  int m  = (bid / CTOT) % NM;
  int b  = bid / (CTOT*NM);
  int lo = level_of(dd);
  int dl = dd - g_coff[lo];
  int ho = g_hL[lo];
  const float* LA = ws + OFF_LA;
  if (t < 6) sla4[t] = LA[(m*CTOT + 276 + t)*CTOT + dd];
  // phase 1: P_l[k''] = sum_{c in level l} La[m,c,dd] * Z_l[b,c,k'']  (levels 0..3)
  for (int s=t; s<340; s+=256){
    int l, kk;
    if (s<4){l=0;kk=s;} else if (s<20){l=1;kk=s-4;} else if (s<84){l=2;kk=s-20;} else {l=3;kk=s-84;}
    int cn = g_cL[l];
    int n = g_hL[l]*g_hL[l];
    const float* zr = ws + OFF_ZRE + b*12288 + g_zo[l] + kk;
    const float* zi = ws + OFF_ZIM + b*12288 + g_zo[l] + kk;
    const float* la = LA + (m*CTOT + g_coff[l])*CTOT + dd;
    float pr=0.f, pi=0.f;
    for (int c=0;c<cn;c++){
      float a = la[c*CTOT];
      pr += a*zr[c*n];
      pi += a*zi[c*n];
    }
    pre[s]=pr; pim[s]=pi;
  }
  __syncthreads();
  // phase 2: fold 1024 aliases through i*lamIm into ho x ho bins
  int nbins = ho*ho;
  float s_out = (float)ho / 1024.0f;
  const float* lamp = ws + OFF_LAM + (m<<10);
  const float* z4r = ws + OFF_ZRE + b*12288 + 6144;
  const float* z4i = ws + OFF_ZIM + b*12288 + 6144;
  float* vR = ws + OFF_VRE + (size_t)(b*NM+m)*12288 + g_zo[lo] + dl*nbins;
  float* vI = ws + OFF_VIM + (size_t)(b*NM+m)*12288 + g_zo[lo] + dl*nbins;

  auto alias_acc = [&](int ky, int kx, float& aR, float& aI){
    int k = (ky<<5) | kx;
    float Ar = pre[((ky&1)<<1)|(kx&1)]
             + pre[4  + ((((ky&3)<<2))|(kx&3))]
             + pre[20 + ((((ky&7)<<3))|(kx&7))]
             + pre[84 + ((((ky&15)<<4))|(kx&15))];
    float Ai = pim[((ky&1)<<1)|(kx&1)]
             + pim[4  + ((((ky&3)<<2))|(kx&3))]
             + pim[20 + ((((ky&7)<<3))|(kx&7))]
             + pim[84 + ((((ky&15)<<4))|(kx&15))];
    #pragma unroll
    for (int c=0;c<6;c++){
      float a4 = sla4[c];
      Ar += a4*z4r[(c<<10)+k];
      Ai += a4*z4i[(c<<10)+k];
    }
    float lm = lamp[k];        // v_fft = A * (i*lm)
    aR -= Ai*lm;
    aI += Ar*lm;
  };

  int nj = 32 / ho;
  if (nbins >= 256){
    int bpt = nbins >> 8;
    int na  = 1024 / nbins;
    for (int ib=0; ib<bpt; ib++){
      int bin = t + (ib<<8);
      int kpy = bin / ho, kpx = bin - (bin/ho)*ho;
      float aR=0.f, aI=0.f;
      for (int a=0;a<na;a++){
        int jy = a / nj, jx = a - (a/nj)*nj;
        alias_acc(kpy + ho*jy, kpx + ho*jx, aR, aI);
      }
      vR[bin]=aR*s_out; vI[bin]=aI*s_out;
    }
  } else {
    int g    = 256 / nbins;
    int bin  = t % nbins;
    int slot = t / nbins;
    int kpy = bin / ho, kpx = bin - (bin/ho)*ho;
    float aR=0.f, aI=0.f;
    for (int i=0;i<4;i++){
      int a = slot*4 + i;
      int jy = a / nj, jx = a - (a/nj)*nj;
      alias_acc(kpy + ho*jy, kpx + ho*jx, aR, aI);
    }
    redR[t]=aR; redI[t]=aI;
    __syncthreads();
    if (t < nbins){
      float rr=0.f, ri=0.f;
      for (int s2=0;s2<g;s2++){ rr+=redR[t+nbins*s2]; ri+=redI[t+nbins*s2]; }
      vR[t]=rr*s_out; vI[t]=ri*s_out;
    }
  }
}

// S_zz gram + S_zw over K=24576 reals (re+im planar), atomic accumulation
__global__ void __launch_bounds__(256) k_gram(float* __restrict__ ws){
  __shared__ float tile[32*257];
  __shared__ float wv[256];
  int t = threadIdx.x;
  int bid = blockIdx.x;
  int b = bid / 96, ch = bid % 96;
  int half = ch / 48;
  int k0 = (ch % 48) * 256;
  const float* V = ws + (half?OFF_VIM:OFF_VRE);
  const float* W = ws + (half?OFF_WIM:OFF_WRE) + b*12288 + k0;
  for (int i=t;i<32*256;i+=256){
    int r=i>>8, c=i&255;
    tile[r*257+c] = V[(size_t)(b*NM+r)*12288 + k0 + c];
  }
  wv[t] = W[t];
  __syncthreads();
  for (int i=0;i<4;i++){
    int p = t + (i<<8);
    int n = p>>5, mm = p&31;
    const float* rn = tile + n*257;
    const float* rm = tile + mm*257;
    float acc=0.f;
    for (int k=0;k<256;k++) acc += rn[k]*rm[k];
    atomicAdd(&ws[OFF_SZZ + (b<<10) + p], acc);
  }
  if (t < 32){
    const float* rn = tile + t*257;
    float acc=0.f;
    for (int k=0;k<256;k++) acc += rn[k]*wv[k];
    atomicAdd(&ws[OFF_SZW + (b<<5) + t], acc);
  }
}

// var, normalize, Cholesky 32x32 in LDS, logdet, trace, output
__global__ void k_final(float* __restrict__ ws, float* __restrict__ out){
  __shared__ float A[32][33];
  __shared__ float svar;
  int b = blockIdx.x, t = threadIdx.x;
  const float* szz = ws + OFF_SZZ + (b<<10);
  if (t==0){
    float s=0.f;
    for (int i=0;i<32;i++) s += szz[i*33];
    svar = fmaxf(s/32.0f, 1e-6f);
  }
  __syncthreads();
  float var = svar;
  for (int i=t;i<1024;i+=64){
    int r=i>>5, c=i&31;
    A[r][c] = szz[i]/var + ((r==c)?EPSV:0.0f);
  }
  __syncthreads();
  for (int j=0;j<32;j++){
    if (t==0) A[j][j] = sqrtf(A[j][j]);
    __syncthreads();
    if (t>j && t<32) A[t][j] /= A[j][j];
    __syncthreads();
    if (t>j && t<32){
      float lij = A[t][j];
      for (int k=j+1;k<=t;k++) A[t][k] -= lij*A[k][j];
    }
    __syncthreads();
  }
  if (t==0){
    float logdet=0.f;
    for (int j=0;j<32;j++) logdet += logf(A[j][j]);
    logdet *= 2.0f;
    const float* szw = ws + OFF_SZW + (b<<5);
    float s2=0.f;
    for (int n=0;n<32;n++) s2 += szw[n]*szw[n];
    float trace = EPSV*ws[OFF_SWW + b] + s2/var;
    out[b] = 0.5f*(logdet - trace);
  }
}

extern "C" void kernel_launch(void* const* d_in, const int* in_sizes, int n_in,
                              void* d_out, int out_size, void* d_ws, size_t ws_size,
                              hipStream_t stream){
  // setup_inputs() dict order is INTERLEAVED: z0,w0,z1,w1,z2,w2,z3,w3,z4,w4,L,lam
  const float* z0 = (const float*)d_in[0];
  const float* w0 = (const float*)d_in[1];
  const float* z1 = (const float*)d_in[2];
  const float* w1 = (const float*)d_in[3];
  const float* z2 = (const float*)d_in[4];
  const float* w2 = (const float*)d_in[5];
  const float* z3 = (const float*)d_in[6];
  const float* w3 = (const float*)d_in[7];
  const float* z4 = (const float*)d_in[8];
  const float* w4 = (const float*)d_in[9];
  const float* L   = (const float*)d_in[10];
  const float* lam = (const float*)d_in[11];
  float* ws = (float*)d_ws;
  float* out = (float*)d_out;

  int prep_n = N_LA + NM*1024;
  k_prep<<<(prep_n+255)/256, 256, 0, stream>>>(L, lam, ws);
  k_dft<<<2*NB*CTOT, 64, 0, stream>>>(z0,z1,z2,z3,z4,w0,w1,w2,w3,w4, ws);
  k_sww<<<NB, 256, 0, stream>>>(w0,w1,w2,w3,w4, ws);
  hipMemsetAsync((char*)d_ws + (size_t)OFF_SZZ*4, 0, (size_t)(NB*NM*NM + NB*NM)*4, stream);
  k_fold<<<NB*NM*CTOT, 256, 0, stream>>>(ws);
  k_gram<<<NB*96, 256, 0, stream>>>(ws);
  k_final<<<NB, 64, 0, stream>>>(ws, out);
}

// Round 3
// 317.967 us; speedup vs baseline: 5.1290x; 5.1290x over previous
//
#include <hip/hip_runtime.h>
#include <math.h>

#define NB 4
#define NM 32
#define CTOT 282
#define EPSV 1e-3f

// per-level constants: channels, spatial size, channel offset, per-batch freq offset
__constant__ int g_cL[5]   = {192,48,24,12,6};
__constant__ int g_hL[5]   = {2,4,8,16,32};
__constant__ int g_coff[5] = {0,192,240,264,276};
__constant__ int g_zo[5]   = {0,768,1536,3072,6144};
__constant__ int g_po[4]   = {0,4,20,84};      // offsets of levels 0..3 inside a 340-pack

// workspace layout (float offsets)
#define N_LA     (NM*CTOT*CTOT)                /* 2544768 */
#define OFF_LAT  0                             /* LaT[m][d][c] = L[m,c,d]-L[m,d,c] */
#define OFF_ZRE  (OFF_LAT + N_LA)
#define OFF_ZIM  (OFF_ZRE + NB*12288)
#define OFF_WRE  (OFF_ZIM + NB*12288)
#define OFF_WIM  (OFF_WRE + NB*12288)
#define OFF_LAM  (OFF_WIM + NB*12288)          /* lamA[m][1024] */
#define OFF_LAMF (OFF_LAM + NM*1024)           /* lamfold[m][340] levels 0..3 */
#define OFF_UR   (OFF_LAMF + NM*340)           /* U[b,m,c4][340] re */
#define OFF_UI   (OFF_UR + NB*NM*6*340)
#define OFF_VRE  (OFF_UI + NB*NM*6*340)
#define OFF_VIM  (OFF_VRE + NB*NM*12288)
#define OFF_SZZ  (OFF_VIM + NB*NM*12288)
#define OFF_SZW  (OFF_SZZ + NB*NM*NM)
#define OFF_SWW  (OFF_SZW + NB*NM)

__device__ __forceinline__ int level_of(int c){
  return (c < 192) ? 0 : (c < 240) ? 1 : (c < 264) ? 2 : (c < 276) ? 3 : 4;
}

// tiled antisymmetrize + transpose: LaT[m][d][c] = L[m][c][d] - L[m][d][c]
__global__ void k_lat(const float* __restrict__ L, float* __restrict__ ws){
  __shared__ float A[32][33], Bt[32][33];
  int bid = blockIdx.x;
  int m = bid/81; int tl = bid%81;
  int d0 = (tl/9)*32, c0 = (tl%9)*32;
  int t = threadIdx.x;
  const float* Lm = L + (size_t)m*CTOT*CTOT;
  for (int i=t;i<1024;i+=256){
    int r=i>>5, c=i&31;
    A[r][c]  = (c0+r<CTOT && d0+c<CTOT) ? Lm[(c0+r)*CTOT + d0+c] : 0.f;  // L[m][c0+r][d0+c]
    Bt[r][c] = (d0+r<CTOT && c0+c<CTOT) ? Lm[(d0+r)*CTOT + c0+c] : 0.f;  // L[m][d0+r][c0+c]
  }
  __syncthreads();
  float* out = ws + OFF_LAT + (size_t)m*CTOT*CTOT;
  for (int i=t;i<1024;i+=256){
    int r=i>>5, c=i&31;   // d = d0+r, cc = c0+c
    if (d0+r<CTOT && c0+c<CTOT)
      out[(size_t)(d0+r)*CTOT + c0+c] = A[c][r] - Bt[r][c];
  }
}

// lamA[m,k] = lam[m,k]-lam[m,-k]; lamfold_l = hierarchical 2x2 folds (levels 3..0)
__global__ void k_lamf(const float* __restrict__ lam, float* __restrict__ ws){
  __shared__ float sA[1024], f3[256], f2[64], f1[16];
  int m = blockIdx.x, t = threadIdx.x;
  for (int k=t;k<1024;k+=256){
    int ky=k>>5, kx=k&31;
    int nk = (((32-ky)&31)<<5) | ((32-kx)&31);
    float v = lam[(m<<10)+k] - lam[(m<<10)+nk];
    sA[k]=v;
    ws[OFF_LAM+(m<<10)+k]=v;
  }
  __syncthreads();
  { int s=t; int ky=s>>4, kx=s&15;
    float v = sA[(ky<<5)+kx]+sA[((ky+16)<<5)+kx]+sA[(ky<<5)+kx+16]+sA[((ky+16)<<5)+kx+16];
    f3[s]=v; ws[OFF_LAMF+m*340+84+s]=v; }
  __syncthreads();
  if (t<64){ int ky=t>>3, kx=t&7;
    float v = f3[(ky<<4)+kx]+f3[((ky+8)<<4)+kx]+f3[(ky<<4)+kx+8]+f3[((ky+8)<<4)+kx+8];
    f2[t]=v; ws[OFF_LAMF+m*340+20+t]=v; }
  __syncthreads();
  if (t<16){ int ky=t>>2, kx=t&3;
    float v = f2[(ky<<3)+kx]+f2[((ky+4)<<3)+kx]+f2[(ky<<3)+kx+4]+f2[((ky+4)<<3)+kx+4];
    f1[t]=v; ws[OFF_LAMF+m*340+4+t]=v; }
  __syncthreads();
  if (t<4){ int ky=t>>1, kx=t&1;
    float v = f1[(ky<<2)+kx]+f1[((ky+2)<<2)+kx]+f1[(ky<<2)+kx+2]+f1[((ky+2)<<2)+kx+2];
    ws[OFF_LAMF+m*340+t]=v; }
}

// small separable 2D DFTs of z levels (unscaled) and w levels (scaled 1/h)
__global__ void k_dft(const float* z0,const float* z1,const float* z2,const float* z3,const float* z4,
                      const float* w0,const float* w1,const float* w2,const float* w3,const float* w4,
                      float* __restrict__ ws){
  __shared__ float sIn[1024], s1r[1024], s1i[1024], lc[32], lsn[32];
  int t = threadIdx.x;
  int bid = blockIdx.x;
  int which = bid / (NB*CTOT);
  int rem = bid % (NB*CTOT);
  int b = rem / CTOT, cg = rem % CTOT;
  int l = level_of(cg);
  int cl = cg - g_coff[l];
  int h = g_hL[l], n = h*h;
  const float* src;
  switch (which*5 + l){
    case 0: src=z0; break; case 1: src=z1; break; case 2: src=z2; break;
    case 3: src=z3; break; case 4: src=z4; break;
    case 5: src=w0; break; case 6: src=w1; break; case 7: src=w2; break;
    case 8: src=w3; break; default: src=w4; break;
  }
  for (int i=t;i<n;i+=64) sIn[i] = src[(b*g_cL[l] + cl)*n + i];
  for (int j=t;j<h;j+=64){
    float ang = -6.2831853071795864f * (float)j / (float)h;
    lc[j] = cosf(ang); lsn[j] = sinf(ang);
  }
  __syncthreads();
  for (int p=t;p<n;p+=64){
    int y=p/h, kx=p-y*h;
    float re=0.f, im=0.f;
    for (int x=0;x<h;x++){
      int id = (kx*x)%h;
      float v = sIn[y*h+x];
      re += v*lc[id]; im += v*lsn[id];
    }
    s1r[p]=re; s1i[p]=im;
  }
  __syncthreads();
  float scale = which ? 1.0f/(float)h : 1.0f;   // W pre-scaled by 1/h for Parseval
  float* outR = ws + (which?OFF_WRE:OFF_ZRE) + b*12288 + g_zo[l] + cl*n;
  float* outI = ws + (which?OFF_WIM:OFF_ZIM) + b*12288 + g_zo[l] + cl*n;
  for (int p=t;p<n;p+=64){
    int ky=p/h, kx=p-(p/h)*h;
    float re=0.f, im=0.f;
    for (int y=0;y<h;y++){
      int id=(ky*y)%h;
      float c=lc[id], s=lsn[id];
      float ar=s1r[y*h+kx], ai=s1i[y*h+kx];
      re += ar*c - ai*s;
      im += ar*s + ai*c;
    }
    outR[p]=re*scale; outI[p]=im*scale;
  }
}

__global__ void k_sww(const float* w0,const float* w1,const float* w2,const float* w3,const float* w4,
                      float* __restrict__ ws){
  __shared__ float red[256];
  int b = blockIdx.x, t = threadIdx.x;
  const float* ptr[5] = {w0,w1,w2,w3,w4};
  float s = 0.f;
  for (int l=0;l<5;l++){
    int sz = g_cL[l]*g_hL[l]*g_hL[l];
    const float* p = ptr[l] + b*sz;
    for (int i=t;i<sz;i+=256){ float v=p[i]; s += v*v; }
  }
  red[t]=s; __syncthreads();
  for (int o=128;o>0;o>>=1){ if (t<o) red[t]+=red[t+o]; __syncthreads(); }
  if (t==0) ws[OFF_SWW + b] = red[0];
}

// U[b,m,c4,lout,k'] = sum_{k=k' mod h_out} lamA[m,k]*Z4[b,c4,k]  (levels 0..3 stored)
__global__ void k_u(float* __restrict__ ws){
  __shared__ float pr[1024], pi[1024], q3r[256],q3i[256],q2r[64],q2i[64],q1r[16],q1i[16];
  int bid = blockIdx.x, t = threadIdx.x;
  int c = bid%6; int m = (bid/6)%NM; int b = bid/(6*NM);
  const float* la = ws+OFF_LAM+(m<<10);
  const float* zr = ws+OFF_ZRE+b*12288+6144+(c<<10);
  const float* zi = ws+OFF_ZIM+b*12288+6144+(c<<10);
  for (int k=t;k<1024;k+=256){ float f=la[k]; pr[k]=f*zr[k]; pi[k]=f*zi[k]; }
  __syncthreads();
  size_t base = (size_t)((b*NM+m)*6+c)*340;
  float* UR = ws+OFF_UR+base; float* UI = ws+OFF_UI+base;
  { int s=t; int ky=s>>4, kx=s&15;
    float r = pr[(ky<<5)+kx]+pr[((ky+16)<<5)+kx]+pr[(ky<<5)+kx+16]+pr[((ky+16)<<5)+kx+16];
    float ii= pi[(ky<<5)+kx]+pi[((ky+16)<<5)+kx]+pi[(ky<<5)+kx+16]+pi[((ky+16)<<5)+kx+16];
    q3r[s]=r; q3i[s]=ii; UR[84+s]=r; UI[84+s]=ii; }
  __syncthreads();
  if (t<64){ int ky=t>>3, kx=t&7;
    float r = q3r[(ky<<4)+kx]+q3r[((ky+8)<<4)+kx]+q3r[(ky<<4)+kx+8]+q3r[((ky+8)<<4)+kx+8];
    float ii= q3i[(ky<<4)+kx]+q3i[((ky+8)<<4)+kx]+q3i[(ky<<4)+kx+8]+q3i[((ky+8)<<4)+kx+8];
    q2r[t]=r; q2i[t]=ii; UR[20+t]=r; UI[20+t]=ii; }
  __syncthreads();
  if (t<16){ int ky=t>>2, kx=t&3;
    float r = q2r[(ky<<3)+kx]+q2r[((ky+4)<<3)+kx]+q2r[(ky<<3)+kx+4]+q2r[((ky+4)<<3)+kx+4];
    float ii= q2i[(ky<<3)+kx]+q2i[((ky+4)<<3)+kx]+q2i[(ky<<3)+kx+4]+q2i[((ky+4)<<3)+kx+4];
    q1r[t]=r; q1i[t]=ii; UR[4+t]=r; UI[4+t]=ii; }
  __syncthreads();
  if (t<4){ int ky=t>>1, kx=t&1;
    float r = q1r[(ky<<2)+kx]+q1r[((ky+2)<<2)+kx]+q1r[(ky<<2)+kx+2]+q1r[((ky+2)<<2)+kx+2];
    float ii= q1i[(ky<<2)+kx]+q1i[((ky+2)<<2)+kx]+q1i[(ky<<2)+kx+2]+q1i[((ky+2)<<2)+kx+2];
    UR[t]=r; UI[t]=ii; }
}

// hot kernel v3: per (b,m,d): balanced P compute, then closed-form fold via lamfold/U
__global__ void __launch_bounds__(256) k_fold(float* __restrict__ ws){
  __shared__ float pre[340], pim[340];
  __shared__ float partr[512], parti[512];
  __shared__ float c256r[256], c256i[256], c64r[64], c64i[64], c16r[16], c16i[16], c4r[4], c4i[4];
  __shared__ float lamf[340], sla4[6];
  int t = threadIdx.x, bid = blockIdx.x;
  int dd = bid % CTOT;
  int m  = (bid / CTOT) % NM;
  int b  = bid / (CTOT*NM);
  int lo = level_of(dd);
  int dl = dd - g_coff[lo];
  int ho = g_hL[lo];
  int nbins = ho*ho;
  const float* laT = ws + OFF_LAT + (size_t)(m*CTOT + dd)*CTOT;   // contiguous over c
  for (int i=t;i<340;i+=256) lamf[i] = ws[OFF_LAMF + m*340 + i];
  if (t<6) sla4[t] = laT[276+t];
  const float* zreb = ws + OFF_ZRE + b*12288;
  const float* zimb = ws + OFF_ZIM + b*12288;
  // phase 1: P_l[k''] via 512 balanced tasks (12 channels each)
  for (int tk=t; tk<512; tk+=256){
    int l, kk, c0;
    if (tk<64){ l=0; kk=tk&3; c0=(tk>>2)*12; }
    else if (tk<128){ int i=tk-64; l=1; kk=i&15; c0=(i>>4)*12; }
    else if (tk<256){ int i=tk-128; l=2; kk=i&63; c0=(i>>6)*12; }
    else { l=3; kk=tk-256; c0=0; }
    int n = g_hL[l]*g_hL[l];
    const float* zr = zreb + g_zo[l] + kk;
    const float* zi = zimb + g_zo[l] + kk;
    const float* la = laT + g_coff[l] + c0;
    float pr=0.f, pii=0.f;
    #pragma unroll
    for (int c=0;c<12;c++){
      float a = la[c];
      pr  += a*zr[(c0+c)*n];
      pii += a*zi[(c0+c)*n];
    }
    partr[tk]=pr; parti[tk]=pii;
  }
  __syncthreads();
  for (int s=t; s<340; s+=256){
    float r=0.f, ii=0.f;
    if (s<4){ for (int ch=0;ch<16;ch++){ r+=partr[(ch<<2)|s]; ii+=parti[(ch<<2)|s]; } }
    else if (s<20){ int kk=s-4; for (int ch=0;ch<4;ch++){ r+=partr[64+((ch<<4)|kk)]; ii+=parti[64+((ch<<4)|kk)]; } }
    else if (s<84){ int kk=s-20; for (int ch=0;ch<2;ch++){ r+=partr[128+((ch<<6)|kk)]; ii+=parti[128+((ch<<6)|kk)]; } }
    else { r=partr[256+(s-84)]; ii=parti[256+(s-84)]; }
    pre[s]=r; pim[s]=ii;
  }
  __syncthreads();
  float sc = (float)ho/1024.f;
  float* vR = ws + OFF_VRE + (size_t)(b*NM+m)*12288 + g_zo[lo] + dl*nbins;
  float* vI = ws + OFF_VIM + (size_t)(b*NM+m)*12288 + g_zo[lo] + dl*nbins;
  if (lo==4){
    const float* laA = ws + OFF_LAM + (m<<10);
    const float* z4r = zreb + 6144;
    const float* z4i = zimb + 6144;
    for (int q=t;q<1024;q+=256){
      int ky=q>>5, kx=q&31;
      float Br = pre[((ky&1)<<1)|(kx&1)] + pre[4+(((ky&3)<<2)|(kx&3))]
               + pre[20+(((ky&7)<<3)|(kx&7))] + pre[84+(((ky&15)<<4)|(kx&15))];
      float Bi = pim[((ky&1)<<1)|(kx&1)] + pim[4+(((ky&3)<<2)|(kx&3))]
               + pim[20+(((ky&7)<<3)|(kx&7))] + pim[84+(((ky&15)<<4)|(kx&15))];
      #pragma unroll
      for (int c=0;c<6;c++){ float a=sla4[c]; Br += a*z4r[(c<<10)+q]; Bi += a*z4i[(c<<10)+q]; }
      float lm = laA[q];
      vR[q] = -sc*(lm*Bi);
      vI[q] =  sc*(lm*Br);
    }
    return;
  }
  // E-chain: fold lamfold_lin*P_lin from finer levels down to ho (exclude lin==lo)
  if (lo<3){ float f=lamf[84+t]; c256r[t]=f*pre[84+t]; c256i[t]=f*pim[84+t]; }
  __syncthreads();
  if (lo<3 && t<64){
    int ky=t>>3, kx=t&7;
    float r = c256r[(ky<<4)+kx]+c256r[((ky+8)<<4)+kx]+c256r[(ky<<4)+kx+8]+c256r[((ky+8)<<4)+kx+8];
    float ii= c256i[(ky<<4)+kx]+c256i[((ky+8)<<4)+kx]+c256i[(ky<<4)+kx+8]+c256i[((ky+8)<<4)+kx+8];
    if (lo<2){ float f=lamf[20+t]; r += f*pre[20+t]; ii += f*pim[20+t]; }
    c64r[t]=r; c64i[t]=ii;
  }
  __syncthreads();
  if (lo<2 && t<16){
    int ky=t>>2, kx=t&3;
    float r = c64r[(ky<<3)+kx]+c64r[((ky+4)<<3)+kx]+c64r[(ky<<3)+kx+4]+c64r[((ky+4)<<3)+kx+4];
    float ii= c64i[(ky<<3)+kx]+c64i[((ky+4)<<3)+kx]+c64i[(ky<<3)+kx+4]+c64i[((ky+4)<<3)+kx+4];
    if (lo<1){ float f=lamf[4+t]; r += f*pre[4+t]; ii += f*pim[4+t]; }
    c16r[t]=r; c16i[t]=ii;
  }
  __syncthreads();
  if (lo==0 && t<4){
    int ky=t>>1, kx=t&1;
    c4r[t]=c16r[(ky<<2)+kx]+c16r[((ky+2)<<2)+kx]+c16r[(ky<<2)+kx+2]+c16r[((ky+2)<<2)+kx+2];
    c4i[t]=c16i[(ky<<2)+kx]+c16i[((ky+2)<<2)+kx]+c16i[(ky<<2)+kx+2]+c16i[((ky+2)<<2)+kx+2];
  }
  __syncthreads();
  if (t<nbins){
    int ky=t/ho, kx=t-ky*ho;
    float Br = pre[((ky&1)<<1)|(kx&1)], Bi = pim[((ky&1)<<1)|(kx&1)];
    if (lo>=1){ int ix=4+(((ky&3)<<2)|(kx&3)); Br+=pre[ix]; Bi+=pim[ix]; }
    if (lo>=2){ int ix=20+(((ky&7)<<3)|(kx&7)); Br+=pre[ix]; Bi+=pim[ix]; }
    if (lo>=3){ int ix=84+(((ky&15)<<4)|(kx&15)); Br+=pre[ix]; Bi+=pim[ix]; }
    float lf = lamf[g_po[lo]+t];
    float Vr = lf*Br, Vi = lf*Bi;
    if (lo==2){ Vr+=c64r[t]; Vi+=c64i[t]; }
    else if (lo==1){ Vr+=c16r[t]; Vi+=c16i[t]; }
    else if (lo==0){ Vr+=c4r[t]; Vi+=c4i[t]; }
    const float* UR = ws + OFF_UR + (size_t)((b*NM+m)*6)*340 + g_po[lo] + t;
    const float* UI = ws + OFF_UI + (size_t)((b*NM+m)*6)*340 + g_po[lo] + t;
    #pragma unroll
    for (int c=0;c<6;c++){ float a=sla4[c]; Vr += a*UR[c*340]; Vi += a*UI[c*340]; }
    vR[t] = -sc*Vi;
    vI[t] =  sc*Vr;
  }
}

// S_zz gram + S_zw over K=24576 reals (re+im planar), atomic accumulation
__global__ void __launch_bounds__(256) k_gram(float* __restrict__ ws){
  __shared__ float tile[32*257];
  __shared__ float wv[256];
  int t = threadIdx.x;
  int bid = blockIdx.x;
  int b = bid / 96, ch = bid % 96;
  int half = ch / 48;
  int k0 = (ch % 48) * 256;
  const float* V = ws + (half?OFF_VIM:OFF_VRE);
  const float* W = ws + (half?OFF_WIM:OFF_WRE) + b*12288 + k0;
  for (int i=t;i<32*256;i+=256){
    int r=i>>8, c=i&255;
    tile[r*257+c] = V[(size_t)(b*NM+r)*12288 + k0 + c];
  }
  wv[t] = W[t];
  __syncthreads();
  for (int i=0;i<4;i++){
    int p = t + (i<<8);
    int n = p>>5, mm = p&31;
    const float* rn = tile + n*257;
    const float* rm = tile + mm*257;
    float acc=0.f;
    for (int k=0;k<256;k++) acc += rn[k]*rm[k];
    atomicAdd(&ws[OFF_SZZ + (b<<10) + p], acc);
  }
  if (t < 32){
    const float* rn = tile + t*257;
    float acc=0.f;
    for (int k=0;k<256;k++) acc += rn[k]*wv[k];
    atomicAdd(&ws[OFF_SZW + (b<<5) + t], acc);
  }
}

// var, normalize, Cholesky 32x32 in LDS, logdet, trace, output
__global__ void k_final(float* __restrict__ ws, float* __restrict__ out){
  __shared__ float A[32][33];
  __shared__ float svar;
  int b = blockIdx.x, t = threadIdx.x;
  const float* szz = ws + OFF_SZZ + (b<<10);
  if (t==0){
    float s=0.f;
    for (int i=0;i<32;i++) s += szz[i*33];
    svar = fmaxf(s/32.0f, 1e-6f);
  }
  __syncthreads();
  float var = svar;
  for (int i=t;i<1024;i+=64){
    int r=i>>5, c=i&31;
    A[r][c] = szz[i]/var + ((r==c)?EPSV:0.0f);
  }
  __syncthreads();
  for (int j=0;j<32;j++){
    if (t==0) A[j][j] = sqrtf(A[j][j]);
    __syncthreads();
    if (t>j && t<32) A[t][j] /= A[j][j];
    __syncthreads();
    if (t>j && t<32){
      float lij = A[t][j];
      for (int k=j+1;k<=t;k++) A[t][k] -= lij*A[k][j];
    }
    __syncthreads();
  }
  if (t==0){
    float logdet=0.f;
    for (int j=0;j<32;j++) logdet += logf(A[j][j]);
    logdet *= 2.0f;
    const float* szw = ws + OFF_SZW + (b<<5);
    float s2=0.f;
    for (int n=0;n<32;n++) s2 += szw[n]*szw[n];
    float trace = EPSV*ws[OFF_SWW + b] + s2/var;
    out[b] = 0.5f*(logdet - trace);
  }
}

extern "C" void kernel_launch(void* const* d_in, const int* in_sizes, int n_in,
                              void* d_out, int out_size, void* d_ws, size_t ws_size,
                              hipStream_t stream){
  // setup_inputs() dict order is INTERLEAVED: z0,w0,z1,w1,z2,w2,z3,w3,z4,w4,L,lam
  const float* z0 = (const float*)d_in[0];
  const float* w0 = (const float*)d_in[1];
  const float* z1 = (const float*)d_in[2];
  const float* w1 = (const float*)d_in[3];
  const float* z2 = (const float*)d_in[4];
  const float* w2 = (const float*)d_in[5];
  const float* z3 = (const float*)d_in[6];
  const float* w3 = (const float*)d_in[7];
  const float* z4 = (const float*)d_in[8];
  const float* w4 = (const float*)d_in[9];
  const float* L   = (const float*)d_in[10];
  const float* lam = (const float*)d_in[11];
  float* ws = (float*)d_ws;
  float* out = (float*)d_out;

  k_lat<<<NM*81, 256, 0, stream>>>(L, ws);
  k_lamf<<<NM, 256, 0, stream>>>(lam, ws);
  k_dft<<<2*NB*CTOT, 64, 0, stream>>>(z0,z1,z2,z3,z4,w0,w1,w2,w3,w4, ws);
  k_sww<<<NB, 256, 0, stream>>>(w0,w1,w2,w3,w4, ws);
  k_u<<<NB*NM*6, 256, 0, stream>>>(ws);
  hipMemsetAsync((char*)d_ws + (size_t)OFF_SZZ*4, 0, (size_t)(NB*NM*NM + NB*NM)*4, stream);
  k_fold<<<NB*NM*CTOT, 256, 0, stream>>>(ws);
  k_gram<<<NB*96, 256, 0, stream>>>(ws);
  k_final<<<NB, 64, 0, stream>>>(ws, out);
}

// Round 4
// 267.362 us; speedup vs baseline: 6.0997x; 1.1893x over previous
//
#include <hip/hip_runtime.h>
#include <math.h>

#define NB 4
#define NM 32
#define CTOT 282
#define EPSV 1e-3f

// per-level constants: channels, spatial size, channel offset, per-batch freq offset
__constant__ int g_cL[5]   = {192,48,24,12,6};
__constant__ int g_hL[5]   = {2,4,8,16,32};
__constant__ int g_coff[5] = {0,192,240,264,276};
__constant__ int g_zo[5]   = {0,768,1536,3072,6144};
__constant__ int g_po[4]   = {0,4,20,84};      // offsets of levels 0..3 inside a 340-pack

// d-tile tables: 36 tiles covering the 282 output channels, level-homogeneous
__constant__ int t_lo[36] = {0,0,0,0,0,0,0,0,0,0,0,0,0,0,0,0,0,0,0,0,0,0,0,0,
                             1,1,1,1,1,1, 2,2,2, 3,3, 4};
__constant__ int t_d0[36] = {0,8,16,24,32,40,48,56,64,72,80,88,96,104,112,120,
                             128,136,144,152,160,168,176,184,
                             192,200,208,216,224,232, 240,248,256, 264,270, 276};
__constant__ int t_nd[36] = {8,8,8,8,8,8,8,8,8,8,8,8,8,8,8,8,8,8,8,8,8,8,8,8,
                             8,8,8,8,8,8, 8,8,8, 6,6, 6};

// workspace layout (float offsets)
#define N_LA     (NM*CTOT*CTOT)                /* 2544768 */
#define OFF_LAT  0                             /* LaT[m][d][c] = L[m,c,d]-L[m,d,c] */
#define OFF_ZRE  (OFF_LAT + N_LA)
#define OFF_ZIM  (OFF_ZRE + NB*12288)
#define OFF_WRE  (OFF_ZIM + NB*12288)
#define OFF_WIM  (OFF_WRE + NB*12288)
#define OFF_LAM  (OFF_WIM + NB*12288)          /* lamA[m][1024] */
#define OFF_LAMF (OFF_LAM + NM*1024)           /* lamfold[m][340] levels 0..3 */
#define OFF_UR   (OFF_LAMF + NM*340)           /* U[b,m,c4][340] re */
#define OFF_UI   (OFF_UR + NB*NM*6*340)
#define OFF_VRE  (OFF_UI + NB*NM*6*340)
#define OFF_VIM  (OFF_VRE + NB*NM*12288)
#define OFF_SZZ  (OFF_VIM + NB*NM*12288)
#define OFF_SZW  (OFF_SZZ + NB*NM*NM)
#define OFF_SWW  (OFF_SZW + NB*NM)

__device__ __forceinline__ int level_of(int c){
  return (c < 192) ? 0 : (c < 240) ? 1 : (c < 264) ? 2 : (c < 276) ? 3 : 4;
}

// merged prep: LaT transpose-antisymmetrize + lamA/lamfold + SZZ/SZW zeroing
__global__ void k_prep2(const float* __restrict__ L, const float* __restrict__ lam,
                        float* __restrict__ ws){
  __shared__ float A[32][33], Bt[32][33];
  __shared__ float sA[1024], f3[256], f2[64], f1[16];
  int bid = blockIdx.x, t = threadIdx.x;
  if (bid < NM*81){
    int m = bid/81; int tl = bid%81;
    int d0 = (tl/9)*32, c0 = (tl%9)*32;
    const float* Lm = L + (size_t)m*CTOT*CTOT;
    for (int i=t;i<1024;i+=256){
      int r=i>>5, c=i&31;
      A[r][c]  = (c0+r<CTOT && d0+c<CTOT) ? Lm[(c0+r)*CTOT + d0+c] : 0.f;
      Bt[r][c] = (d0+r<CTOT && c0+c<CTOT) ? Lm[(d0+r)*CTOT + c0+c] : 0.f;
    }
    __syncthreads();
    float* out = ws + OFF_LAT + (size_t)m*CTOT*CTOT;
    for (int i=t;i<1024;i+=256){
      int r=i>>5, c=i&31;
      if (d0+r<CTOT && c0+c<CTOT)
        out[(size_t)(d0+r)*CTOT + c0+c] = A[c][r] - Bt[r][c];
    }
    return;
  }
  if (bid < NM*81 + NM){
    int m = bid - NM*81;
    for (int k=t;k<1024;k+=256){
      int ky=k>>5, kx=k&31;
      int nk = (((32-ky)&31)<<5) | ((32-kx)&31);
      float v = lam[(m<<10)+k] - lam[(m<<10)+nk];
      sA[k]=v;
      ws[OFF_LAM+(m<<10)+k]=v;
    }
    __syncthreads();
    { int s=t; int ky=s>>4, kx=s&15;
      float v = sA[(ky<<5)+kx]+sA[((ky+16)<<5)+kx]+sA[(ky<<5)+kx+16]+sA[((ky+16)<<5)+kx+16];
      f3[s]=v; ws[OFF_LAMF+m*340+84+s]=v; }
    __syncthreads();
    if (t<64){ int ky=t>>3, kx=t&7;
      float v = f3[(ky<<4)+kx]+f3[((ky+8)<<4)+kx]+f3[(ky<<4)+kx+8]+f3[((ky+8)<<4)+kx+8];
      f2[t]=v; ws[OFF_LAMF+m*340+20+t]=v; }
    __syncthreads();
    if (t<16){ int ky=t>>2, kx=t&3;
      float v = f2[(ky<<3)+kx]+f2[((ky+4)<<3)+kx]+f2[(ky<<3)+kx+4]+f2[((ky+4)<<3)+kx+4];
      f1[t]=v; ws[OFF_LAMF+m*340+4+t]=v; }
    __syncthreads();
    if (t<4){ int ky=t>>1, kx=t&1;
      float v = f1[(ky<<2)+kx]+f1[((ky+2)<<2)+kx]+f1[(ky<<2)+kx+2]+f1[((ky+2)<<2)+kx+2];
      ws[OFF_LAMF+m*340+t]=v; }
    return;
  }
  int i = (bid - (NM*81+NM))*256 + t;
  if (i < NB*NM*NM + NB*NM) ws[OFF_SZZ + i] = 0.f;
}

// small separable 2D DFTs of z levels (unscaled) and w levels (scaled 1/h)
__global__ void k_dft(const float* z0,const float* z1,const float* z2,const float* z3,const float* z4,
                      const float* w0,const float* w1,const float* w2,const float* w3,const float* w4,
                      float* __restrict__ ws){
  __shared__ float sIn[1024], s1r[1024], s1i[1024], lc[32], lsn[32];
  int t = threadIdx.x;
  int bid = blockIdx.x;
  int which = bid / (NB*CTOT);
  int rem = bid % (NB*CTOT);
  int b = rem / CTOT, cg = rem % CTOT;
  int l = level_of(cg);
  int cl = cg - g_coff[l];
  int h = g_hL[l], n = h*h;
  const float* src;
  switch (which*5 + l){
    case 0: src=z0; break; case 1: src=z1; break; case 2: src=z2; break;
    case 3: src=z3; break; case 4: src=z4; break;
    case 5: src=w0; break; case 6: src=w1; break; case 7: src=w2; break;
    case 8: src=w3; break; default: src=w4; break;
  }
  for (int i=t;i<n;i+=64) sIn[i] = src[(b*g_cL[l] + cl)*n + i];
  for (int j=t;j<h;j+=64){
    float ang = -6.2831853071795864f * (float)j / (float)h;
    lc[j] = cosf(ang); lsn[j] = sinf(ang);
  }
  __syncthreads();
  for (int p=t;p<n;p+=64){
    int y=p/h, kx=p-y*h;
    float re=0.f, im=0.f;
    for (int x=0;x<h;x++){
      int id = (kx*x)%h;
      float v = sIn[y*h+x];
      re += v*lc[id]; im += v*lsn[id];
    }
    s1r[p]=re; s1i[p]=im;
  }
  __syncthreads();
  float scale = which ? 1.0f/(float)h : 1.0f;   // W pre-scaled by 1/h for Parseval
  float* outR = ws + (which?OFF_WRE:OFF_ZRE) + b*12288 + g_zo[l] + cl*n;
  float* outI = ws + (which?OFF_WIM:OFF_ZIM) + b*12288 + g_zo[l] + cl*n;
  for (int p=t;p<n;p+=64){
    int ky=p/h, kx=p-(p/h)*h;
    float re=0.f, im=0.f;
    for (int y=0;y<h;y++){
      int id=(ky*y)%h;
      float c=lc[id], s=lsn[id];
      float ar=s1r[y*h+kx], ai=s1i[y*h+kx];
      re += ar*c - ai*s;
      im += ar*s + ai*c;
    }
    outR[p]=re*scale; outI[p]=im*scale;
  }
}

// U[b,m,c4,lout,k'] folds of lamA*Z4, merged with S_ww reduction
__global__ void k_u2(float* __restrict__ ws,
                     const float* w0,const float* w1,const float* w2,const float* w3,const float* w4){
  __shared__ float pr[1024], pi[1024], q3r[256],q3i[256],q2r[64],q2i[64],q1r[16],q1i[16];
  __shared__ float red[256];
  int bid = blockIdx.x, t = threadIdx.x;
  if (bid < NB*NM*6){
    int c = bid%6; int m = (bid/6)%NM; int b = bid/(6*NM);
    const float* la = ws+OFF_LAM+(m<<10);
    const float* zr = ws+OFF_ZRE+b*12288+6144+(c<<10);
    const float* zi = ws+OFF_ZIM+b*12288+6144+(c<<10);
    for (int k=t;k<1024;k+=256){ float f=la[k]; pr[k]=f*zr[k]; pi[k]=f*zi[k]; }
    __syncthreads();
    size_t base = (size_t)((b*NM+m)*6+c)*340;
    float* UR = ws+OFF_UR+base; float* UI = ws+OFF_UI+base;
    { int s=t; int ky=s>>4, kx=s&15;
      float r = pr[(ky<<5)+kx]+pr[((ky+16)<<5)+kx]+pr[(ky<<5)+kx+16]+pr[((ky+16)<<5)+kx+16];
      float ii= pi[(ky<<5)+kx]+pi[((ky+16)<<5)+kx]+pi[(ky<<5)+kx+16]+pi[((ky+16)<<5)+kx+16];
      q3r[s]=r; q3i[s]=ii; UR[84+s]=r; UI[84+s]=ii; }
    __syncthreads();
    if (t<64){ int ky=t>>3, kx=t&7;
      float r = q3r[(ky<<4)+kx]+q3r[((ky+8)<<4)+kx]+q3r[(ky<<4)+kx+8]+q3r[((ky+8)<<4)+kx+8];
      float ii= q3i[(ky<<4)+kx]+q3i[((ky+8)<<4)+kx]+q3i[(ky<<4)+kx+8]+q3i[((ky+8)<<4)+kx+8];
      q2r[t]=r; q2i[t]=ii; UR[20+t]=r; UI[20+t]=ii; }
    __syncthreads();
    if (t<16){ int ky=t>>2, kx=t&3;
      float r = q2r[(ky<<3)+kx]+q2r[((ky+4)<<3)+kx]+q2r[(ky<<3)+kx+4]+q2r[((ky+4)<<3)+kx+4];
      float ii= q2i[(ky<<3)+kx]+q2i[((ky+4)<<3)+kx]+q2i[(ky<<3)+kx+4]+q2i[((ky+4)<<3)+kx+4];
      q1r[t]=r; q1i[t]=ii; UR[4+t]=r; UI[4+t]=ii; }
    __syncthreads();
    if (t<4){ int ky=t>>1, kx=t&1;
      float r = q1r[(ky<<2)+kx]+q1r[((ky+2)<<2)+kx]+q1r[(ky<<2)+kx+2]+q1r[((ky+2)<<2)+kx+2];
      float ii= q1i[(ky<<2)+kx]+q1i[((ky+2)<<2)+kx]+q1i[(ky<<2)+kx+2]+q1i[((ky+2)<<2)+kx+2];
      UR[t]=r; UI[t]=ii; }
    return;
  }
  // S_ww part
  int b = bid - NB*NM*6;
  const float* ptr[5] = {w0,w1,w2,w3,w4};
  float s = 0.f;
  for (int l=0;l<5;l++){
    int sz = g_cL[l]*g_hL[l]*g_hL[l];
    const float* p = ptr[l] + b*sz;
    for (int i=t;i<sz;i+=256){ float v=p[i]; s += v*v; }
  }
  red[t]=s; __syncthreads();
  for (int o=128;o>0;o>>=1){ if (t<o) red[t]+=red[t+o]; __syncthreads(); }
  if (t==0) ws[OFF_SWW + b] = red[0];
}

// hot kernel v4: d-tiled — Z in registers reused across 6-8 d's, La/U staged in LDS
__global__ void __launch_bounds__(256) k_fold(float* __restrict__ ws){
  __shared__ float smem[12196];
  float* partr = smem;            // 2048 = 8x256  (later: chain cf / staged U re)
  float* parti = smem + 2048;     // 2048          (later: chain cf / staged U im)
  float* pre   = smem + 4096;     // 2720 = 8x340
  float* pim   = smem + 6816;     // 2720
  float* sLa   = smem + 9536;     // 2272 = 8x284 (16B-aligned rows; dead after phase 1)
  float* c64r  = smem + 9536;     // 512  (chain buffers overlay sLa)
  float* c64i  = smem + 10048;    // 512
  float* c16r  = smem + 10560;    // 128
  float* c16i  = smem + 10688;    // 128
  float* c4r   = smem + 10816;    // 32
  float* c4i   = smem + 10848;    // 32
  float* lamf  = smem + 11808;    // 340
  float* ssla  = smem + 12148;    // 48 = 8x6

  int t = threadIdx.x, bid = blockIdx.x;
  int tile = bid % 36;
  int m = (bid/36) % NM;
  int b = bid / (36*NM);
  int lo = t_lo[tile], d0 = t_d0[tile], nd = t_nd[tile];
  int ho = g_hL[lo];
  int nbins = ho*ho;
  const float* zreb = ws + OFF_ZRE + b*12288;
  const float* zimb = ws + OFF_ZIM + b*12288;
  const float* latm = ws + OFF_LAT + (size_t)m*CTOT*CTOT;

  // stage La rows, lamfold, la4 coefficients
  for (int i=t;i<340;i+=256) lamf[i] = ws[OFF_LAMF + m*340 + i];
  for (int i=t;i<nd*282;i+=256){ int d=i/282, c=i-d*282; sLa[d*284+c] = latm[(size_t)(d0+d)*CTOT + c]; }
  if (t<nd*6){ int d=t/6, c=t-d*6; ssla[t] = latm[(size_t)(d0+d)*CTOT + 276 + c]; }

  // taskA (levels 0..2) + taskB (level 3) z-fragments into registers, once per block
  int lA, kkA, c0A, nA;
  if (t<64){ lA=0; kkA=t&3; c0A=(t>>2)*12; nA=4; }
  else if (t<128){ int i=t-64; lA=1; kkA=i&15; c0A=(i>>4)*12; nA=16; }
  else { int i=t-128; lA=2; kkA=i&63; c0A=(i>>6)*12; nA=64; }
  float zAr[12], zAi[12], zBr[12], zBi[12];
  {
    const float* zr = zreb + g_zo[lA] + kkA;
    const float* zi = zimb + g_zo[lA] + kkA;
    #pragma unroll
    for (int c=0;c<12;c++){ zAr[c]=zr[(c0A+c)*nA]; zAi[c]=zi[(c0A+c)*nA]; }
    const float* zr3 = zreb + 3072 + t;
    const float* zi3 = zimb + 3072 + t;
    #pragma unroll
    for (int c=0;c<12;c++){ zBr[c]=zr3[c*256]; zBi[c]=zi3[c*256]; }
  }
  __syncthreads();

  // phase 1: per-d partials, reusing z registers
  int offA = g_coff[lA] + c0A;
  for (int d=0; d<nd; d++){
    const float* la = sLa + d*284;
    float prA=0.f, piA=0.f, prB=0.f, piB=0.f;
    #pragma unroll
    for (int c=0;c<12;c++){ float a=la[offA+c]; prA+=a*zAr[c]; piA+=a*zAi[c]; }
    #pragma unroll
    for (int c=0;c<12;c++){ float a=la[264+c]; prB+=a*zBr[c]; piB+=a*zBi[c]; }
    partr[(d<<8)+t]=prA; parti[(d<<8)+t]=piA;
    pre[d*340+84+t]=prB; pim[d*340+84+t]=piB;
  }
  __syncthreads();

  // reduce levels 0..2 partials into pre[0..84)
  for (int idx=t; idx<nd*84; idx+=256){
    int d=idx/84, s=idx-d*84;
    int base=d<<8;
    float r=0.f, ii=0.f;
    if (s<4){ for (int ch=0;ch<16;ch++){ int p=base+((ch<<2)|s); r+=partr[p]; ii+=parti[p]; } }
    else if (s<20){ int kk=s-4; for (int ch=0;ch<4;ch++){ int p=base+64+((ch<<4)|kk); r+=partr[p]; ii+=parti[p]; } }
    else { int kk=s-20; for (int ch=0;ch<2;ch++){ int p=base+128+((ch<<6)|kk); r+=partr[p]; ii+=parti[p]; } }
    pre[d*340+s]=r; pim[d*340+s]=ii;
  }
  __syncthreads();

  float sc = (float)ho/1024.f;
  if (lo==4){
    const float* lamA = ws + OFF_LAM + (m<<10);
    float* vRb = ws + OFF_VRE + (size_t)(b*NM+m)*12288 + 6144;
    float* vIb = ws + OFF_VIM + (size_t)(b*NM+m)*12288 + 6144;
    const float* z4r = zreb + 6144;
    const float* z4i = zimb + 6144;
    for (int q=t; q<1024; q+=256){
      int ky=q>>5, kx=q&31;
      int a0=((ky&1)<<1)|(kx&1);
      int a1=4+(((ky&3)<<2)|(kx&3));
      int a2=20+(((ky&7)<<3)|(kx&7));
      int a3=84+(((ky&15)<<4)|(kx&15));
      float zr_[6], zi_[6];
      #pragma unroll
      for (int c=0;c<6;c++){ zr_[c]=z4r[(c<<10)+q]; zi_[c]=z4i[(c<<10)+q]; }
      float lm = lamA[q]*sc;
      for (int d=0; d<6; d++){
        const float* pd = pre + d*340; const float* qd = pim + d*340;
        float Br = pd[a0]+pd[a1]+pd[a2]+pd[a3];
        float Bi = qd[a0]+qd[a1]+qd[a2]+qd[a3];
        #pragma unroll
        for (int c=0;c<6;c++){ float a=ssla[d*6+c]; Br+=a*zr_[c]; Bi+=a*zi_[c]; }
        vRb[(d<<10)+q] = -lm*Bi;
        vIb[(d<<10)+q] =  lm*Br;
      }
    }
    return;
  }

  // E-chain, batched over the tile's d's
  if (lo<3){
    for (int idx=t; idx<nd*256; idx+=256){
      int d=idx>>8, k=idx&255;
      float f=lamf[84+k];
      partr[idx]=f*pre[d*340+84+k];
      parti[idx]=f*pim[d*340+84+k];
    }
  }
  __syncthreads();
  if (lo<3){
    for (int idx=t; idx<nd*64; idx+=256){
      int d=idx>>6, k2=idx&63, ky=k2>>3, kx=k2&7, base=d<<8;
      float r = partr[base+(ky<<4)+kx]+partr[base+((ky+8)<<4)+kx]+partr[base+(ky<<4)+kx+8]+partr[base+((ky+8)<<4)+kx+8];
      float ii= parti[base+(ky<<4)+kx]+parti[base+((ky+8)<<4)+kx]+parti[base+(ky<<4)+kx+8]+parti[base+((ky+8)<<4)+kx+8];
      if (lo<2){ float f=lamf[20+k2]; r+=f*pre[d*340+20+k2]; ii+=f*pim[d*340+20+k2]; }
      c64r[idx]=r; c64i[idx]=ii;
    }
  }
  __syncthreads();
  if (lo<2){
    for (int idx=t; idx<nd*16; idx+=256){
      int d=idx>>4, k2=idx&15, ky=k2>>2, kx=k2&3, base=d<<6;
      float r = c64r[base+(ky<<3)+kx]+c64r[base+((ky+4)<<3)+kx]+c64r[base+(ky<<3)+kx+4]+c64r[base+((ky+4)<<3)+kx+4];
      float ii= c64i[base+(ky<<3)+kx]+c64i[base+((ky+4)<<3)+kx]+c64i[base+(ky<<3)+kx+4]+c64i[base+((ky+4)<<3)+kx+4];
      if (lo<1){ float f=lamf[4+k2]; r+=f*pre[d*340+4+k2]; ii+=f*pim[d*340+4+k2]; }
      c16r[idx]=r; c16i[idx]=ii;
    }
  }
  __syncthreads();
  if (lo==0 && t<nd*4){
    int d=t>>2, k2=t&3, ky=k2>>1, kx=k2&1, base=d<<4;
    c4r[t]=c16r[base+(ky<<2)+kx]+c16r[base+((ky+2)<<2)+kx]+c16r[base+(ky<<2)+kx+2]+c16r[base+((ky+2)<<2)+kx+2];
    c4i[t]=c16i[base+(ky<<2)+kx]+c16i[base+((ky+2)<<2)+kx]+c16i[base+(ky<<2)+kx+2]+c16i[base+((ky+2)<<2)+kx+2];
  }
  __syncthreads();

  // stage U into the (now free) partr/parti region
  {
    const float* URg = ws + OFF_UR + (size_t)((b*NM+m)*6)*340 + g_po[lo];
    const float* UIg = ws + OFF_UI + (size_t)((b*NM+m)*6)*340 + g_po[lo];
    for (int idx=t; idx<6*nbins; idx+=256){
      int c=idx/nbins, bin=idx-c*nbins;
      partr[idx]=URg[c*340+bin];
      parti[idx]=UIg[c*340+bin];
    }
  }
  __syncthreads();

  int dlb = d0 - g_coff[lo];
  float* vRb = ws + OFF_VRE + (size_t)(b*NM+m)*12288 + g_zo[lo];
  float* vIb = ws + OFF_VIM + (size_t)(b*NM+m)*12288 + g_zo[lo];
  for (int idx=t; idx<nd*nbins; idx+=256){
    int d=idx/nbins, bin=idx-d*nbins;
    int ky=bin/ho, kx=bin-ky*ho;
    const float* pd = pre + d*340; const float* qd = pim + d*340;
    float Br = pd[((ky&1)<<1)|(kx&1)], Bi = qd[((ky&1)<<1)|(kx&1)];
    if (lo>=1){ int ix=4+(((ky&3)<<2)|(kx&3)); Br+=pd[ix]; Bi+=qd[ix]; }
    if (lo>=2){ int ix=20+(((ky&7)<<3)|(kx&7)); Br+=pd[ix]; Bi+=qd[ix]; }
    if (lo>=3){ int ix=84+(((ky&15)<<4)|(kx&15)); Br+=pd[ix]; Bi+=qd[ix]; }
    float lf = lamf[g_po[lo]+bin];
    float Vr = lf*Br, Vi = lf*Bi;
    if (lo==2){ Vr+=c64r[(d<<6)+bin]; Vi+=c64i[(d<<6)+bin]; }
    else if (lo==1){ Vr+=c16r[(d<<4)+bin]; Vi+=c16i[(d<<4)+bin]; }
    else if (lo==0){ Vr+=c4r[(d<<2)+bin]; Vi+=c4i[(d<<2)+bin]; }
    #pragma unroll
    for (int c=0;c<6;c++){ float a=ssla[d*6+c]; Vr+=a*partr[c*nbins+bin]; Vi+=a*parti[c*nbins+bin]; }
    int ob = (dlb+d)*nbins + bin;
    vRb[ob] = -sc*Vi;
    vIb[ob] =  sc*Vr;
  }
}

// S_zz gram + S_zw over K=24576 reals (re+im planar), atomic accumulation
__global__ void __launch_bounds__(256) k_gram(float* __restrict__ ws){
  __shared__ float tile[32*257];
  __shared__ float wv[256];
  int t = threadIdx.x;
  int bid = blockIdx.x;
  int b = bid / 96, ch = bid % 96;
  int half = ch / 48;
  int k0 = (ch % 48) * 256;
  const float* V = ws + (half?OFF_VIM:OFF_VRE);
  const float* W = ws + (half?OFF_WIM:OFF_WRE) + b*12288 + k0;
  for (int i=t;i<32*256;i+=256){
    int r=i>>8, c=i&255;
    tile[r*257+c] = V[(size_t)(b*NM+r)*12288 + k0 + c];
  }
  wv[t] = W[t];
  __syncthreads();
  for (int i=0;i<4;i++){
    int p = t + (i<<8);
    int n = p>>5, mm = p&31;
    const float* rn = tile + n*257;
    const float* rm = tile + mm*257;
    float acc=0.f;
    for (int k=0;k<256;k++) acc += rn[k]*rm[k];
    atomicAdd(&ws[OFF_SZZ + (b<<10) + p], acc);
  }
  if (t < 32){
    const float* rn = tile + t*257;
    float acc=0.f;
    for (int k=0;k<256;k++) acc += rn[k]*wv[k];
    atomicAdd(&ws[OFF_SZW + (b<<5) + t], acc);
  }
}

// var, normalize, Cholesky 32x32 in LDS, logdet, trace, output
__global__ void k_final(float* __restrict__ ws, float* __restrict__ out){
  __shared__ float A[32][33];
  __shared__ float svar;
  int b = blockIdx.x, t = threadIdx.x;
  const float* szz = ws + OFF_SZZ + (b<<10);
  if (t==0){
    float s=0.f;
    for (int i=0;i<32;i++) s += szz[i*33];
    svar = fmaxf(s/32.0f, 1e-6f);
  }
  __syncthreads();
  float var = svar;
  for (int i=t;i<1024;i+=64){
    int r=i>>5, c=i&31;
    A[r][c] = szz[i]/var + ((r==c)?EPSV:0.0f);
  }
  __syncthreads();
  for (int j=0;j<32;j++){
    if (t==0) A[j][j] = sqrtf(A[j][j]);
    __syncthreads();
    if (t>j && t<32) A[t][j] /= A[j][j];
    __syncthreads();
    if (t>j && t<32){
      float lij = A[t][j];
      for (int k=j+1;k<=t;k++) A[t][k] -= lij*A[k][j];
    }
    __syncthreads();
  }
  if (t==0){
    float logdet=0.f;
    for (int j=0;j<32;j++) logdet += logf(A[j][j]);
    logdet *= 2.0f;
    const float* szw = ws + OFF_SZW + (b<<5);
    float s2=0.f;
    for (int n=0;n<32;n++) s2 += szw[n]*szw[n];
    float trace = EPSV*ws[OFF_SWW + b] + s2/var;
    out[b] = 0.5f*(logdet - trace);
  }
}

extern "C" void kernel_launch(void* const* d_in, const int* in_sizes, int n_in,
                              void* d_out, int out_size, void* d_ws, size_t ws_size,
                              hipStream_t stream){
  // setup_inputs() dict order is INTERLEAVED: z0,w0,z1,w1,z2,w2,z3,w3,z4,w4,L,lam
  const float* z0 = (const float*)d_in[0];
  const float* w0 = (const float*)d_in[1];
  const float* z1 = (const float*)d_in[2];
  const float* w1 = (const float*)d_in[3];
  const float* z2 = (const float*)d_in[4];
  const float* w2 = (const float*)d_in[5];
  const float* z3 = (const float*)d_in[6];
  const float* w3 = (const float*)d_in[7];
  const float* z4 = (const float*)d_in[8];
  const float* w4 = (const float*)d_in[9];
  const float* L   = (const float*)d_in[10];
  const float* lam = (const float*)d_in[11];
  float* ws = (float*)d_ws;
  float* out = (float*)d_out;

  int zero_blocks = (NB*NM*NM + NB*NM + 255)/256;
  k_prep2<<<NM*81 + NM + zero_blocks, 256, 0, stream>>>(L, lam, ws);
  k_dft<<<2*NB*CTOT, 64, 0, stream>>>(z0,z1,z2,z3,z4,w0,w1,w2,w3,w4, ws);
  k_u2<<<NB*NM*6 + NB, 256, 0, stream>>>(ws, w0,w1,w2,w3,w4);
  k_fold<<<NB*NM*36, 256, 0, stream>>>(ws);
  k_gram<<<NB*96, 256, 0, stream>>>(ws);
  k_final<<<NB, 64, 0, stream>>>(ws, out);
}

// Round 5
// 219.436 us; speedup vs baseline: 7.4320x; 1.2184x over previous
//
#include <hip/hip_runtime.h>
#include <math.h>

#define NB 4
#define NM 32
#define CTOT 282
#define EPSV 1e-3f

__constant__ int g_cL[5]   = {192,48,24,12,6};
__constant__ int g_hL[5]   = {2,4,8,16,32};
__constant__ int g_coff[5] = {0,192,240,264,276};
__constant__ int g_zo[5]   = {0,768,1536,3072,6144};
__constant__ int g_po[4]   = {0,4,20,84};

// d-tile tables: 36 tiles covering the 282 output channels, level-homogeneous
__constant__ int t_lo[36] = {0,0,0,0,0,0,0,0,0,0,0,0,0,0,0,0,0,0,0,0,0,0,0,0,
                             1,1,1,1,1,1, 2,2,2, 3,3, 4};
__constant__ int t_d0[36] = {0,8,16,24,32,40,48,56,64,72,80,88,96,104,112,120,
                             128,136,144,152,160,168,176,184,
                             192,200,208,216,224,232, 240,248,256, 264,270, 276};
__constant__ int t_nd[36] = {8,8,8,8,8,8,8,8,8,8,8,8,8,8,8,8,8,8,8,8,8,8,8,8,
                             8,8,8,8,8,8, 8,8,8, 6,6, 6};

// dft sub-block tables (30 per (which,b)): level + channel offset
__constant__ int dft_l[30]  = {0,0,0, 1,1,1, 2,2,2,2,2,2,
                               3,3,3,3,3,3,3,3,3,3,3,3, 4,4,4,4,4,4};
__constant__ int dft_c0[30] = {0,64,128, 0,16,32, 0,4,8,12,16,20,
                               0,1,2,3,4,5,6,7,8,9,10,11, 0,1,2,3,4,5};
__constant__ int dft_nc[30] = {64,64,64, 16,16,16, 4,4,4,4,4,4,
                               1,1,1,1,1,1,1,1,1,1,1,1, 1,1,1,1,1,1};

// workspace layout (float offsets)
#define N_LA     (NM*CTOT*CTOT)
#define OFF_LAT  0
#define OFF_ZRE  (OFF_LAT + N_LA)
#define OFF_ZIM  (OFF_ZRE + NB*12288)
#define OFF_WRE  (OFF_ZIM + NB*12288)
#define OFF_WIM  (OFF_WRE + NB*12288)
#define OFF_LAM  (OFF_WIM + NB*12288)
#define OFF_LAMF (OFF_LAM + NM*1024)
#define OFF_UR   (OFF_LAMF + NM*340)
#define OFF_UI   (OFF_UR + NB*NM*6*340)
#define OFF_VRE  (OFF_UI + NB*NM*6*340)
#define OFF_VIM  (OFF_VRE + NB*NM*12288)
#define OFF_SZZ  (OFF_VIM + NB*NM*12288)
#define OFF_SZW  (OFF_SZZ + NB*NM*NM)
#define OFF_SWW  (OFF_SZW + NB*NM)

// k_pre bid ranges
#define PRE_LAT   (NM*81)                 /* 2592 */
#define PRE_LAMF  (PRE_LAT + NM)          /* +32  */
#define PRE_DFT   (PRE_LAMF + 2*NB*30)    /* +240 */
#define PRE_SWW   (PRE_DFT + NB)          /* +4   */
#define PRE_ZERO  (PRE_SWW + 17)          /* +17  */

// merged: LaT transpose + lamA/lamfold + DFTs + S_ww + SZZ zeroing
__global__ void __launch_bounds__(256) k_pre(
    const float* z0,const float* z1,const float* z2,const float* z3,const float* z4,
    const float* w0,const float* w1,const float* w2,const float* w3,const float* w4,
    const float* __restrict__ L, const float* __restrict__ lam, float* __restrict__ ws){
  __shared__ float shm[3136];
  int bid = blockIdx.x, t = threadIdx.x;
  if (bid < PRE_LAT){
    float* A  = shm;          // 32x33
    float* Bt = shm + 1056;   // 32x33
    int m = bid/81; int tl = bid%81;
    int d0 = (tl/9)*32, c0 = (tl%9)*32;
    const float* Lm = L + (size_t)m*CTOT*CTOT;
    for (int i=t;i<1024;i+=256){
      int r=i>>5, c=i&31;
      A[r*33+c]  = (c0+r<CTOT && d0+c<CTOT) ? Lm[(c0+r)*CTOT + d0+c] : 0.f;
      Bt[r*33+c] = (d0+r<CTOT && c0+c<CTOT) ? Lm[(d0+r)*CTOT + c0+c] : 0.f;
    }
    __syncthreads();
    float* out = ws + OFF_LAT + (size_t)m*CTOT*CTOT;
    for (int i=t;i<1024;i+=256){
      int r=i>>5, c=i&31;
      if (d0+r<CTOT && c0+c<CTOT)
        out[(size_t)(d0+r)*CTOT + c0+c] = A[c*33+r] - Bt[r*33+c];
    }
    return;
  }
  if (bid < PRE_LAMF){
    float* sA = shm;          // 1024
    float* f3 = shm + 1024;   // 256
    float* f2 = shm + 1280;   // 64
    float* f1 = shm + 1344;   // 16
    int m = bid - PRE_LAT;
    for (int k=t;k<1024;k+=256){
      int ky=k>>5, kx=k&31;
      int nk = (((32-ky)&31)<<5) | ((32-kx)&31);
      float v = lam[(m<<10)+k] - lam[(m<<10)+nk];
      sA[k]=v;
      ws[OFF_LAM+(m<<10)+k]=v;
    }
    __syncthreads();
    { int s=t; int ky=s>>4, kx=s&15;
      float v = sA[(ky<<5)+kx]+sA[((ky+16)<<5)+kx]+sA[(ky<<5)+kx+16]+sA[((ky+16)<<5)+kx+16];
      f3[s]=v; ws[OFF_LAMF+m*340+84+s]=v; }
    __syncthreads();
    if (t<64){ int ky=t>>3, kx=t&7;
      float v = f3[(ky<<4)+kx]+f3[((ky+8)<<4)+kx]+f3[(ky<<4)+kx+8]+f3[((ky+8)<<4)+kx+8];
      f2[t]=v; ws[OFF_LAMF+m*340+20+t]=v; }
    __syncthreads();
    if (t<16){ int ky=t>>2, kx=t&3;
      float v = f2[(ky<<3)+kx]+f2[((ky+4)<<3)+kx]+f2[(ky<<3)+kx+4]+f2[((ky+4)<<3)+kx+4];
      f1[t]=v; ws[OFF_LAMF+m*340+4+t]=v; }
    __syncthreads();
    if (t<4){ int ky=t>>1, kx=t&1;
      float v = f1[(ky<<2)+kx]+f1[((ky+2)<<2)+kx]+f1[(ky<<2)+kx+2]+f1[((ky+2)<<2)+kx+2];
      ws[OFF_LAMF+m*340+t]=v; }
    return;
  }
  if (bid < PRE_DFT){
    float* sIn = shm;          // 1024
    float* s1r = shm + 1024;   // 1024
    float* s1i = shm + 2048;   // 1024
    float* lc  = shm + 3072;   // 32
    float* lsn = shm + 3104;   // 32
    int i0 = bid - PRE_LAMF;
    int which = i0 / (NB*30);
    int rem = i0 % (NB*30);
    int b = rem / 30, j = rem % 30;
    int l = dft_l[j], c0 = dft_c0[j], nc = dft_nc[j];
    int h = g_hL[l], n = h*h;
    int elems = nc*n;
    const float* src;
    switch (which*5 + l){
      case 0: src=z0; break; case 1: src=z1; break; case 2: src=z2; break;
      case 3: src=z3; break; case 4: src=z4; break;
      case 5: src=w0; break; case 6: src=w1; break; case 7: src=w2; break;
      case 8: src=w3; break; default: src=w4; break;
    }
    for (int i=t;i<elems;i+=256) sIn[i] = src[(b*g_cL[l] + c0)*n + i];
    if (t<h){
      float ang = -6.2831853071795864f * (float)t / (float)h;
      lc[t] = cosf(ang); lsn[t] = sinf(ang);
    }
    __syncthreads();
    for (int p=t;p<elems;p+=256){
      int p2=p%n, cc=p/n;
      int y=p2/h, kx=p2-y*h;
      float re=0.f, im=0.f;
      for (int x=0;x<h;x++){
        int id = (kx*x)%h;
        float v = sIn[cc*n + y*h + x];
        re += v*lc[id]; im += v*lsn[id];
      }
      s1r[p]=re; s1i[p]=im;
    }
    __syncthreads();
    float scale = which ? 1.0f/(float)h : 1.0f;
    float* outR = ws + (which?OFF_WRE:OFF_ZRE) + b*12288 + g_zo[l] + c0*n;
    float* outI = ws + (which?OFF_WIM:OFF_ZIM) + b*12288 + g_zo[l] + c0*n;
    for (int p=t;p<elems;p+=256){
      int p2=p%n, cc=p/n;
      int ky=p2/h, kx=p2-(p2/h)*h;
      float re=0.f, im=0.f;
      for (int y=0;y<h;y++){
        int id=(ky*y)%h;
        float c=lc[id], s=lsn[id];
        float ar=s1r[cc*n + y*h + kx], ai=s1i[cc*n + y*h + kx];
        re += ar*c - ai*s;
        im += ar*s + ai*c;
      }
      outR[p]=re*scale; outI[p]=im*scale;
    }
    return;
  }
  if (bid < PRE_SWW){
    float* red = shm;
    int b = bid - PRE_DFT;
    const float* ptr[5] = {w0,w1,w2,w3,w4};
    float s = 0.f;
    for (int l=0;l<5;l++){
      int sz = g_cL[l]*g_hL[l]*g_hL[l];
      const float* p = ptr[l] + b*sz;
      for (int i=t;i<sz;i+=256){ float v=p[i]; s += v*v; }
    }
    red[t]=s; __syncthreads();
    for (int o=128;o>0;o>>=1){ if (t<o) red[t]+=red[t+o]; __syncthreads(); }
    if (t==0) ws[OFF_SWW + b] = red[0];
    return;
  }
  int i = (bid - PRE_SWW)*256 + t;
  if (i < NB*NM*NM + NB*NM) ws[OFF_SZZ + i] = 0.f;
}

// U[b,m,c4,lout,k'] folds of lamA*Z4
__global__ void k_u(float* __restrict__ ws){
  __shared__ float pr[1024], pi[1024], q3r[256],q3i[256],q2r[64],q2i[64],q1r[16],q1i[16];
  int bid = blockIdx.x, t = threadIdx.x;
  int c = bid%6; int m = (bid/6)%NM; int b = bid/(6*NM);
  const float* la = ws+OFF_LAM+(m<<10);
  const float* zr = ws+OFF_ZRE+b*12288+6144+(c<<10);
  const float* zi = ws+OFF_ZIM+b*12288+6144+(c<<10);
  for (int k=t;k<1024;k+=256){ float f=la[k]; pr[k]=f*zr[k]; pi[k]=f*zi[k]; }
  __syncthreads();
  size_t base = (size_t)((b*NM+m)*6+c)*340;
  float* UR = ws+OFF_UR+base; float* UI = ws+OFF_UI+base;
  { int s=t; int ky=s>>4, kx=s&15;
    float r = pr[(ky<<5)+kx]+pr[((ky+16)<<5)+kx]+pr[(ky<<5)+kx+16]+pr[((ky+16)<<5)+kx+16];
    float ii= pi[(ky<<5)+kx]+pi[((ky+16)<<5)+kx]+pi[(ky<<5)+kx+16]+pi[((ky+16)<<5)+kx+16];
    q3r[s]=r; q3i[s]=ii; UR[84+s]=r; UI[84+s]=ii; }
  __syncthreads();
  if (t<64){ int ky=t>>3, kx=t&7;
    float r = q3r[(ky<<4)+kx]+q3r[((ky+8)<<4)+kx]+q3r[(ky<<4)+kx+8]+q3r[((ky+8)<<4)+kx+8];
    float ii= q3i[(ky<<4)+kx]+q3i[((ky+8)<<4)+kx]+q3i[(ky<<4)+kx+8]+q3i[((ky+8)<<4)+kx+8];
    q2r[t]=r; q2i[t]=ii; UR[20+t]=r; UI[20+t]=ii; }
  __syncthreads();
  if (t<16){ int ky=t>>2, kx=t&3;
    float r = q2r[(ky<<3)+kx]+q2r[((ky+4)<<3)+kx]+q2r[(ky<<3)+kx+4]+q2r[((ky+4)<<3)+kx+4];
    float ii= q2i[(ky<<3)+kx]+q2i[((ky+4)<<3)+kx]+q2i[(ky<<3)+kx+4]+q2i[((ky+4)<<3)+kx+4];
    q1r[t]=r; q1i[t]=ii; UR[4+t]=r; UI[4+t]=ii; }
  __syncthreads();
  if (t<4){ int ky=t>>1, kx=t&1;
    float r = q1r[(ky<<2)+kx]+q1r[((ky+2)<<2)+kx]+q1r[(ky<<2)+kx+2]+q1r[((ky+2)<<2)+kx+2];
    float ii= q1i[(ky<<2)+kx]+q1i[((ky+2)<<2)+kx]+q1i[(ky<<2)+kx+2]+q1i[((ky+2)<<2)+kx+2];
    UR[t]=r; UI[t]=ii; }
}

// hot kernel v5: d-tiled, shuffle-reduced phase 1, direct c64 chain, global-U combine
// LDS = 9444 floats = 36.9 KB -> 4 blocks/CU
__global__ void __launch_bounds__(256) k_fold(float* __restrict__ ws){
  __shared__ float smem[9444];
  float* pre  = smem;          // 8x340
  float* pim  = smem + 2720;   // 8x340
  float* sLa  = smem + 5440;   // 8x284
  float* c64r = smem + 7712;   // 512
  float* c64i = smem + 8224;   // 512
  float* c16r = smem + 8736;   // 128
  float* c16i = smem + 8864;   // 128
  float* c4r  = smem + 8992;   // 32
  float* c4i  = smem + 9024;   // 32
  float* lamf = smem + 9056;   // 340
  float* ssla = smem + 9396;   // 48

  int t = threadIdx.x, bid = blockIdx.x;
  int tile = bid % 36;
  int m = (bid/36) % NM;
  int b = bid / (36*NM);
  int lo = t_lo[tile], d0 = t_d0[tile], nd = t_nd[tile];
  int ho = g_hL[lo];
  int nbins = ho*ho;
  const float* zreb = ws + OFF_ZRE + b*12288;
  const float* zimb = ws + OFF_ZIM + b*12288;
  const float* latm = ws + OFF_LAT + (size_t)m*CTOT*CTOT;

  for (int i=t;i<340;i+=256) lamf[i] = ws[OFF_LAMF + m*340 + i];
  for (int i=t;i<nd*282;i+=256){ int d=i/282, c=i-d*282; sLa[d*284+c] = latm[(size_t)(d0+d)*CTOT + c]; }
  if (t<nd*6){ int d=t/6, c=t-d*6; ssla[t] = latm[(size_t)(d0+d)*CTOT + 276 + c]; }

  // task mapping: wave0=level0, wave1=level1, waves2-3=level2; all threads also level3
  int lA, kkA, c0A, nA, nred, wrt, offP;
  if (t<64){ lA=0; kkA=t>>4; c0A=(t&15)*12; nA=4; nred=4; wrt=((t&15)==0); offP=0; }
  else if (t<128){ int i=t-64; lA=1; kkA=i>>2; c0A=(i&3)*12; nA=16; nred=2; wrt=((i&3)==0); offP=4; }
  else { int i=t-128; lA=2; kkA=i>>1; c0A=(i&1)*12; nA=64; nred=1; wrt=((i&1)==0); offP=20; }
  float zAr[12], zAi[12], zBr[12], zBi[12];
  {
    const float* zr = zreb + g_zo[lA] + kkA;
    const float* zi = zimb + g_zo[lA] + kkA;
    #pragma unroll
    for (int c=0;c<12;c++){ zAr[c]=zr[(c0A+c)*nA]; zAi[c]=zi[(c0A+c)*nA]; }
    const float* zr3 = zreb + 3072 + t;
    const float* zi3 = zimb + 3072 + t;
    #pragma unroll
    for (int c=0;c<12;c++){ zBr[c]=zr3[c*256]; zBi[c]=zi3[c*256]; }
  }
  __syncthreads();

  // phase 1: per-d partials; in-wave shuffle reduce over channel chunks
  int offA = g_coff[lA] + c0A;
  for (int d=0; d<nd; d++){
    const float* la = sLa + d*284;
    float prA=0.f, piA=0.f, prB=0.f, piB=0.f;
    #pragma unroll
    for (int c=0;c<12;c++){ float a=la[offA+c]; prA+=a*zAr[c]; piA+=a*zAi[c]; }
    #pragma unroll
    for (int c=0;c<12;c++){ float a=la[264+c]; prB+=a*zBr[c]; piB+=a*zBi[c]; }
    if (nred==4){
      prA += __shfl_xor(prA,1); piA += __shfl_xor(piA,1);
      prA += __shfl_xor(prA,2); piA += __shfl_xor(piA,2);
      prA += __shfl_xor(prA,4); piA += __shfl_xor(piA,4);
      prA += __shfl_xor(prA,8); piA += __shfl_xor(piA,8);
    } else if (nred==2){
      prA += __shfl_xor(prA,1); piA += __shfl_xor(piA,1);
      prA += __shfl_xor(prA,2); piA += __shfl_xor(piA,2);
    } else {
      prA += __shfl_xor(prA,1); piA += __shfl_xor(piA,1);
    }
    if (wrt){ pre[d*340 + offP + kkA] = prA; pim[d*340 + offP + kkA] = piA; }
    pre[d*340+84+t] = prB; pim[d*340+84+t] = piB;
  }
  __syncthreads();

  float sc = (float)ho/1024.f;
  if (lo==4){
    const float* lamA = ws + OFF_LAM + (m<<10);
    float* vRb = ws + OFF_VRE + (size_t)(b*NM+m)*12288 + 6144;
    float* vIb = ws + OFF_VIM + (size_t)(b*NM+m)*12288 + 6144;
    const float* z4r = zreb + 6144;
    const float* z4i = zimb + 6144;
    for (int q=t; q<1024; q+=256){
      int ky=q>>5, kx=q&31;
      int a0=((ky&1)<<1)|(kx&1);
      int a1=4+(((ky&3)<<2)|(kx&3));
      int a2=20+(((ky&7)<<3)|(kx&7));
      int a3=84+(((ky&15)<<4)|(kx&15));
      float zr_[6], zi_[6];
      #pragma unroll
      for (int c=0;c<6;c++){ zr_[c]=z4r[(c<<10)+q]; zi_[c]=z4i[(c<<10)+q]; }
      float lm = lamA[q]*sc;
      for (int d=0; d<6; d++){
        const float* pd = pre + d*340; const float* qd = pim + d*340;
        float Br = pd[a0]+pd[a1]+pd[a2]+pd[a3];
        float Bi = qd[a0]+qd[a1]+qd[a2]+qd[a3];
        #pragma unroll
        for (int c=0;c<6;c++){ float a=ssla[d*6+c]; Br+=a*zr_[c]; Bi+=a*zi_[c]; }
        vRb[(d<<10)+q] = -lm*Bi;
        vIb[(d<<10)+q] =  lm*Br;
      }
    }
    return;
  }

  // chain: c64 computed directly from pre (no c256 materialization)
  if (lo<3){
    for (int idx=t; idx<nd*64; idx+=256){
      int d=idx>>6, k2=idx&63, ky=k2>>3, kx=k2&7;
      const float* pd = pre + d*340 + 84; const float* qd = pim + d*340 + 84;
      float r=0.f, ii=0.f;
      #pragma unroll
      for (int jy=0;jy<2;jy++)
        #pragma unroll
        for (int jx=0;jx<2;jx++){
          int a = ((ky+8*jy)<<4) | (kx+8*jx);
          float f = lamf[84+a];
          r += f*pd[a]; ii += f*qd[a];
        }
      if (lo<2){ float f=lamf[20+k2]; r+=f*pre[d*340+20+k2]; ii+=f*pim[d*340+20+k2]; }
      c64r[idx]=r; c64i[idx]=ii;
    }
  }
  __syncthreads();
  if (lo<2){
    for (int idx=t; idx<nd*16; idx+=256){
      int d=idx>>4, k2=idx&15, ky=k2>>2, kx=k2&3, base=d<<6;
      float r = c64r[base+(ky<<3)+kx]+c64r[base+((ky+4)<<3)+kx]+c64r[base+(ky<<3)+kx+4]+c64r[base+((ky+4)<<3)+kx+4];
      float ii= c64i[base+(ky<<3)+kx]+c64i[base+((ky+4)<<3)+kx]+c64i[base+(ky<<3)+kx+4]+c64i[base+((ky+4)<<3)+kx+4];
      if (lo<1){ float f=lamf[4+k2]; r+=f*pre[d*340+4+k2]; ii+=f*pim[d*340+4+k2]; }
      c16r[idx]=r; c16i[idx]=ii;
    }
  }
  __syncthreads();
  if (lo==0 && t<nd*4){
    int d=t>>2, k2=t&3, ky=k2>>1, kx=k2&1, base=d<<4;
    c4r[t]=c16r[base+(ky<<2)+kx]+c16r[base+((ky+2)<<2)+kx]+c16r[base+(ky<<2)+kx+2]+c16r[base+((ky+2)<<2)+kx+2];
    c4i[t]=c16i[base+(ky<<2)+kx]+c16i[base+((ky+2)<<2)+kx]+c16i[base+(ky<<2)+kx+2]+c16i[base+((ky+2)<<2)+kx+2];
  }
  __syncthreads();

  int dlb = d0 - g_coff[lo];
  float* vRb = ws + OFF_VRE + (size_t)(b*NM+m)*12288 + g_zo[lo];
  float* vIb = ws + OFF_VIM + (size_t)(b*NM+m)*12288 + g_zo[lo];
  const float* URg = ws + OFF_UR + (size_t)((b*NM+m)*6)*340 + g_po[lo];
  const float* UIg = ws + OFF_UI + (size_t)((b*NM+m)*6)*340 + g_po[lo];
  for (int idx=t; idx<nd*nbins; idx+=256){
    int d=idx/nbins, bin=idx-d*nbins;
    int ky=bin/ho, kx=bin-ky*ho;
    const float* pd = pre + d*340; const float* qd = pim + d*340;
    float Br = pd[((ky&1)<<1)|(kx&1)], Bi = qd[((ky&1)<<1)|(kx&1)];
    if (lo>=1){ int ix=4+(((ky&3)<<2)|(kx&3)); Br+=pd[ix]; Bi+=qd[ix]; }
    if (lo>=2){ int ix=20+(((ky&7)<<3)|(kx&7)); Br+=pd[ix]; Bi+=qd[ix]; }
    if (lo>=3){ int ix=84+(((ky&15)<<4)|(kx&15)); Br+=pd[ix]; Bi+=qd[ix]; }
    float lf = lamf[g_po[lo]+bin];
    float Vr = lf*Br, Vi = lf*Bi;
    if (lo==2){ Vr+=c64r[(d<<6)+bin]; Vi+=c64i[(d<<6)+bin]; }
    else if (lo==1){ Vr+=c16r[(d<<4)+bin]; Vi+=c16i[(d<<4)+bin]; }
    else if (lo==0){ Vr+=c4r[(d<<2)+bin]; Vi+=c4i[(d<<2)+bin]; }
    #pragma unroll
    for (int c=0;c<6;c++){ float a=ssla[d*6+c]; Vr+=a*URg[c*340+bin]; Vi+=a*UIg[c*340+bin]; }
    int ob = (dlb+d)*nbins + bin;
    vRb[ob] = -sc*Vi;
    vIb[ob] =  sc*Vr;
  }
}

// S_zz gram + S_zw: register-tiled (4 outputs/thread), float4 LDS reads
__global__ void __launch_bounds__(256) k_gram(float* __restrict__ ws){
  __shared__ float tile[32*260];   // row stride 260 floats = 65 float4
  __shared__ float wv[256];
  int t = threadIdx.x;
  int bid = blockIdx.x;
  int b = bid / 96, ch = bid % 96;
  int half = ch / 48;
  int k0 = (ch % 48) * 256;
  const float* V = ws + (half?OFF_VIM:OFF_VRE);
  const float* W = ws + (half?OFF_WIM:OFF_WRE) + b*12288 + k0;
  for (int i=t;i<32*256;i+=256){
    int r=i>>8, c=i&255;
    tile[r*260+c] = V[(size_t)(b*NM+r)*12288 + k0 + c];
  }
  wv[t] = W[t];
  __syncthreads();
  const float4* tf = (const float4*)tile;
  int n0 = t>>5, mm = t&31;
  float acc0=0.f, acc1=0.f, acc2=0.f, acc3=0.f;
  const float4* rm = tf + mm*65;
  const float4* r0 = tf + n0*65;
  const float4* r1 = tf + (n0+8)*65;
  const float4* r2 = tf + (n0+16)*65;
  const float4* r3 = tf + (n0+24)*65;
  for (int k4=0;k4<64;k4++){
    float4 vm = rm[k4];
    float4 v0 = r0[k4];
    float4 v1 = r1[k4];
    float4 v2 = r2[k4];
    float4 v3 = r3[k4];
    acc0 += v0.x*vm.x + v0.y*vm.y + v0.z*vm.z + v0.w*vm.w;
    acc1 += v1.x*vm.x + v1.y*vm.y + v1.z*vm.z + v1.w*vm.w;
    acc2 += v2.x*vm.x + v2.y*vm.y + v2.z*vm.z + v2.w*vm.w;
    acc3 += v3.x*vm.x + v3.y*vm.y + v3.z*vm.z + v3.w*vm.w;
  }
  float* szz = ws + OFF_SZZ + (b<<10);
  atomicAdd(&szz[(n0<<5) + mm], acc0);
  atomicAdd(&szz[((n0+8)<<5) + mm], acc1);
  atomicAdd(&szz[((n0+16)<<5) + mm], acc2);
  atomicAdd(&szz[((n0+24)<<5) + mm], acc3);
  if (t < 32){
    const float4* rn = tf + t*65;
    const float4* wf = (const float4*)wv;
    float acc=0.f;
    for (int k4=0;k4<64;k4++){
      float4 a = rn[k4]; float4 wq = wf[k4];
      acc += a.x*wq.x + a.y*wq.y + a.z*wq.z + a.w*wq.w;
    }
    atomicAdd(&ws[OFF_SZW + (b<<5) + t], acc);
  }
}

// var, normalize, Cholesky 32x32 in LDS, logdet, trace, output
__global__ void k_final(float* __restrict__ ws, float* __restrict__ out){
  __shared__ float A[32][33];
  __shared__ float svar;
  int b = blockIdx.x, t = threadIdx.x;
  const float* szz = ws + OFF_SZZ + (b<<10);
  if (t==0){
    float s=0.f;
    for (int i=0;i<32;i++) s += szz[i*33];
    svar = fmaxf(s/32.0f, 1e-6f);
  }
  __syncthreads();
  float var = svar;
  for (int i=t;i<1024;i+=64){
    int r=i>>5, c=i&31;
    A[r][c] = szz[i]/var + ((r==c)?EPSV:0.0f);
  }
  __syncthreads();
  for (int j=0;j<32;j++){
    if (t==0) A[j][j] = sqrtf(A[j][j]);
    __syncthreads();
    if (t>j && t<32) A[t][j] /= A[j][j];
    __syncthreads();
    if (t>j && t<32){
      float lij = A[t][j];
      for (int k=j+1;k<=t;k++) A[t][k] -= lij*A[k][j];
    }
    __syncthreads();
  }
  if (t==0){
    float logdet=0.f;
    for (int j=0;j<32;j++) logdet += logf(A[j][j]);
    logdet *= 2.0f;
    const float* szw = ws + OFF_SZW + (b<<5);
    float s2=0.f;
    for (int n=0;n<32;n++) s2 += szw[n]*szw[n];
    float trace = EPSV*ws[OFF_SWW + b] + s2/var;
    out[b] = 0.5f*(logdet - trace);
  }
}

extern "C" void kernel_launch(void* const* d_in, const int* in_sizes, int n_in,
                              void* d_out, int out_size, void* d_ws, size_t ws_size,
                              hipStream_t stream){
  // setup_inputs() dict order is INTERLEAVED: z0,w0,z1,w1,z2,w2,z3,w3,z4,w4,L,lam
  const float* z0 = (const float*)d_in[0];
  const float* w0 = (const float*)d_in[1];
  const float* z1 = (const float*)d_in[2];
  const float* w1 = (const float*)d_in[3];
  const float* z2 = (const float*)d_in[4];
  const float* w2 = (const float*)d_in[5];
  const float* z3 = (const float*)d_in[6];
  const float* w3 = (const float*)d_in[7];
  const float* z4 = (const float*)d_in[8];
  const float* w4 = (const float*)d_in[9];
  const float* L   = (const float*)d_in[10];
  const float* lam = (const float*)d_in[11];
  float* ws = (float*)d_ws;
  float* out = (float*)d_out;

  k_pre<<<PRE_ZERO, 256, 0, stream>>>(z0,z1,z2,z3,z4,w0,w1,w2,w3,w4, L, lam, ws);
  k_u<<<NB*NM*6, 256, 0, stream>>>(ws);
  k_fold<<<NB*NM*36, 256, 0, stream>>>(ws);
  k_gram<<<NB*96, 256, 0, stream>>>(ws);
  k_final<<<NB, 64, 0, stream>>>(ws, out);
}

// Round 6
// 213.258 us; speedup vs baseline: 7.6473x; 1.0290x over previous
//
#include <hip/hip_runtime.h>
#include <math.h>

#define NB 4
#define NM 32
#define CTOT 282
#define EPSV 1e-3f

__constant__ int g_cL[5]   = {192,48,24,12,6};
__constant__ int g_hL[5]   = {2,4,8,16,32};
__constant__ int g_coff[5] = {0,192,240,264,276};
__constant__ int g_zo[5]   = {0,768,1536,3072,6144};
__constant__ int g_po[4]   = {0,4,20,84};

// 48 level-homogeneous d-tiles: 32x level0(nd=6), 8x level1, 4x level2, 2x level3, 2x level4(nd=3)
__constant__ int t_lo[48] = {0,0,0,0,0,0,0,0,0,0,0,0,0,0,0,0,
                             0,0,0,0,0,0,0,0,0,0,0,0,0,0,0,0,
                             1,1,1,1,1,1,1,1, 2,2,2,2, 3,3, 4,4};
__constant__ int t_d0[48] = {0,6,12,18,24,30,36,42,48,54,60,66,72,78,84,90,
                             96,102,108,114,120,126,132,138,144,150,156,162,168,174,180,186,
                             192,198,204,210,216,222,228,234, 240,246,252,258, 264,270, 276,279};
__constant__ int t_nd[48] = {6,6,6,6,6,6,6,6,6,6,6,6,6,6,6,6,
                             6,6,6,6,6,6,6,6,6,6,6,6,6,6,6,6,
                             6,6,6,6,6,6,6,6, 6,6,6,6, 6,6, 3,3};

// dft sub-block tables (30 per (which,b)): level + channel offset
__constant__ int dft_l[30]  = {0,0,0, 1,1,1, 2,2,2,2,2,2,
                               3,3,3,3,3,3,3,3,3,3,3,3, 4,4,4,4,4,4};
__constant__ int dft_c0[30] = {0,64,128, 0,16,32, 0,4,8,12,16,20,
                               0,1,2,3,4,5,6,7,8,9,10,11, 0,1,2,3,4,5};
__constant__ int dft_nc[30] = {64,64,64, 16,16,16, 4,4,4,4,4,4,
                               1,1,1,1,1,1,1,1,1,1,1,1, 1,1,1,1,1,1};

// workspace layout (float offsets)
#define N_LA     (NM*CTOT*CTOT)
#define OFF_LAT  0
#define OFF_ZRE  (OFF_LAT + N_LA)
#define OFF_ZIM  (OFF_ZRE + NB*12288)
#define OFF_WRE  (OFF_ZIM + NB*12288)
#define OFF_WIM  (OFF_WRE + NB*12288)
#define OFF_LAM  (OFF_WIM + NB*12288)
#define OFF_LAMF (OFF_LAM + NM*1024)
#define OFF_UR   (OFF_LAMF + NM*340)
#define OFF_UI   (OFF_UR + NB*NM*6*340)
#define OFF_VRE  (OFF_UI + NB*NM*6*340)
#define OFF_VIM  (OFF_VRE + NB*NM*12288)
#define OFF_SZZ  (OFF_VIM + NB*NM*12288)
#define OFF_SZW  (OFF_SZZ + NB*NM*NM)
#define OFF_SWW  (OFF_SZW + NB*NM)

// k_pre bid ranges
#define PRE_LAT   (NM*81)
#define PRE_LAMF  (PRE_LAT + NM)
#define PRE_DFT   (PRE_LAMF + 2*NB*30)
#define PRE_SWW   (PRE_DFT + NB)
#define PRE_ZERO  (PRE_SWW + 17)

// merged: LaT transpose + lamA/lamfold + DFTs + S_ww + SZZ zeroing
__global__ void __launch_bounds__(256) k_pre(
    const float* z0,const float* z1,const float* z2,const float* z3,const float* z4,
    const float* w0,const float* w1,const float* w2,const float* w3,const float* w4,
    const float* __restrict__ L, const float* __restrict__ lam, float* __restrict__ ws){
  __shared__ float shm[3136];
  int bid = blockIdx.x, t = threadIdx.x;
  if (bid < PRE_LAT){
    float* A  = shm;
    float* Bt = shm + 1056;
    int m = bid/81; int tl = bid%81;
    int d0 = (tl/9)*32, c0 = (tl%9)*32;
    const float* Lm = L + (size_t)m*CTOT*CTOT;
    for (int i=t;i<1024;i+=256){
      int r=i>>5, c=i&31;
      A[r*33+c]  = (c0+r<CTOT && d0+c<CTOT) ? Lm[(c0+r)*CTOT + d0+c] : 0.f;
      Bt[r*33+c] = (d0+r<CTOT && c0+c<CTOT) ? Lm[(d0+r)*CTOT + c0+c] : 0.f;
    }
    __syncthreads();
    float* out = ws + OFF_LAT + (size_t)m*CTOT*CTOT;
    for (int i=t;i<1024;i+=256){
      int r=i>>5, c=i&31;
      if (d0+r<CTOT && c0+c<CTOT)
        out[(size_t)(d0+r)*CTOT + c0+c] = A[c*33+r] - Bt[r*33+c];
    }
    return;
  }
  if (bid < PRE_LAMF){
    float* sA = shm;
    float* f3 = shm + 1024;
    float* f2 = shm + 1280;
    float* f1 = shm + 1344;
    int m = bid - PRE_LAT;
    for (int k=t;k<1024;k+=256){
      int ky=k>>5, kx=k&31;
      int nk = (((32-ky)&31)<<5) | ((32-kx)&31);
      float v = lam[(m<<10)+k] - lam[(m<<10)+nk];
      sA[k]=v;
      ws[OFF_LAM+(m<<10)+k]=v;
    }
    __syncthreads();
    { int s=t; int ky=s>>4, kx=s&15;
      float v = sA[(ky<<5)+kx]+sA[((ky+16)<<5)+kx]+sA[(ky<<5)+kx+16]+sA[((ky+16)<<5)+kx+16];
      f3[s]=v; ws[OFF_LAMF+m*340+84+s]=v; }
    __syncthreads();
    if (t<64){ int ky=t>>3, kx=t&7;
      float v = f3[(ky<<4)+kx]+f3[((ky+8)<<4)+kx]+f3[(ky<<4)+kx+8]+f3[((ky+8)<<4)+kx+8];
      f2[t]=v; ws[OFF_LAMF+m*340+20+t]=v; }
    __syncthreads();
    if (t<16){ int ky=t>>2, kx=t&3;
      float v = f2[(ky<<3)+kx]+f2[((ky+4)<<3)+kx]+f2[(ky<<3)+kx+4]+f2[((ky+4)<<3)+kx+4];
      f1[t]=v; ws[OFF_LAMF+m*340+4+t]=v; }
    __syncthreads();
    if (t<4){ int ky=t>>1, kx=t&1;
      float v = f1[(ky<<2)+kx]+f1[((ky+2)<<2)+kx]+f1[(ky<<2)+kx+2]+f1[((ky+2)<<2)+kx+2];
      ws[OFF_LAMF+m*340+t]=v; }
    return;
  }
  if (bid < PRE_DFT){
    float* sIn = shm;
    float* s1r = shm + 1024;
    float* s1i = shm + 2048;
    float* lc  = shm + 3072;
    float* lsn = shm + 3104;
    int i0 = bid - PRE_LAMF;
    int which = i0 / (NB*30);
    int rem = i0 % (NB*30);
    int b = rem / 30, j = rem % 30;
    int l = dft_l[j], c0 = dft_c0[j], nc = dft_nc[j];
    int h = g_hL[l], n = h*h;
    int elems = nc*n;
    const float* src;
    switch (which*5 + l){
      case 0: src=z0; break; case 1: src=z1; break; case 2: src=z2; break;
      case 3: src=z3; break; case 4: src=z4; break;
      case 5: src=w0; break; case 6: src=w1; break; case 7: src=w2; break;
      case 8: src=w3; break; default: src=w4; break;
    }
    for (int i=t;i<elems;i+=256) sIn[i] = src[(b*g_cL[l] + c0)*n + i];
    if (t<h){
      float ang = -6.2831853071795864f * (float)t / (float)h;
      lc[t] = cosf(ang); lsn[t] = sinf(ang);
    }
    __syncthreads();
    for (int p=t;p<elems;p+=256){
      int p2=p%n, cc=p/n;
      int y=p2/h, kx=p2-y*h;
      float re=0.f, im=0.f;
      for (int x=0;x<h;x++){
        int id = (kx*x)%h;
        float v = sIn[cc*n + y*h + x];
        re += v*lc[id]; im += v*lsn[id];
      }
      s1r[p]=re; s1i[p]=im;
    }
    __syncthreads();
    float scale = which ? 1.0f/(float)h : 1.0f;
    float* outR = ws + (which?OFF_WRE:OFF_ZRE) + b*12288 + g_zo[l] + c0*n;
    float* outI = ws + (which?OFF_WIM:OFF_ZIM) + b*12288 + g_zo[l] + c0*n;
    for (int p=t;p<elems;p+=256){
      int p2=p%n, cc=p/n;
      int ky=p2/h, kx=p2-(p2/h)*h;
      float re=0.f, im=0.f;
      for (int y=0;y<h;y++){
        int id=(ky*y)%h;
        float c=lc[id], s=lsn[id];
        float ar=s1r[cc*n + y*h + kx], ai=s1i[cc*n + y*h + kx];
        re += ar*c - ai*s;
        im += ar*s + ai*c;
      }
      outR[p]=re*scale; outI[p]=im*scale;
    }
    return;
  }
  if (bid < PRE_SWW){
    float* red = shm;
    int b = bid - PRE_DFT;
    const float* ptr[5] = {w0,w1,w2,w3,w4};
    float s = 0.f;
    for (int l=0;l<5;l++){
      int sz = g_cL[l]*g_hL[l]*g_hL[l];
      const float* p = ptr[l] + b*sz;
      for (int i=t;i<sz;i+=256){ float v=p[i]; s += v*v; }
    }
    red[t]=s; __syncthreads();
    for (int o=128;o>0;o>>=1){ if (t<o) red[t]+=red[t+o]; __syncthreads(); }
    if (t==0) ws[OFF_SWW + b] = red[0];
    return;
  }
  int i = (bid - PRE_SWW)*256 + t;
  if (i < NB*NM*NM + NB*NM) ws[OFF_SZZ + i] = 0.f;
}

// U[b,m,c4,lout,k'] folds of lamA*Z4
__global__ void k_u(float* __restrict__ ws){
  __shared__ float pr[1024], pi[1024], q3r[256],q3i[256],q2r[64],q2i[64],q1r[16],q1i[16];
  int bid = blockIdx.x, t = threadIdx.x;
  int c = bid%6; int m = (bid/6)%NM; int b = bid/(6*NM);
  const float* la = ws+OFF_LAM+(m<<10);
  const float* zr = ws+OFF_ZRE+b*12288+6144+(c<<10);
  const float* zi = ws+OFF_ZIM+b*12288+6144+(c<<10);
  for (int k=t;k<1024;k+=256){ float f=la[k]; pr[k]=f*zr[k]; pi[k]=f*zi[k]; }
  __syncthreads();
  size_t base = (size_t)((b*NM+m)*6+c)*340;
  float* UR = ws+OFF_UR+base; float* UI = ws+OFF_UI+base;
  { int s=t; int ky=s>>4, kx=s&15;
    float r = pr[(ky<<5)+kx]+pr[((ky+16)<<5)+kx]+pr[(ky<<5)+kx+16]+pr[((ky+16)<<5)+kx+16];
    float ii= pi[(ky<<5)+kx]+pi[((ky+16)<<5)+kx]+pi[(ky<<5)+kx+16]+pi[((ky+16)<<5)+kx+16];
    q3r[s]=r; q3i[s]=ii; UR[84+s]=r; UI[84+s]=ii; }
  __syncthreads();
  if (t<64){ int ky=t>>3, kx=t&7;
    float r = q3r[(ky<<4)+kx]+q3r[((ky+8)<<4)+kx]+q3r[(ky<<4)+kx+8]+q3r[((ky+8)<<4)+kx+8];
    float ii= q3i[(ky<<4)+kx]+q3i[((ky+8)<<4)+kx]+q3i[(ky<<4)+kx+8]+q3i[((ky+8)<<4)+kx+8];
    q2r[t]=r; q2i[t]=ii; UR[20+t]=r; UI[20+t]=ii; }
  __syncthreads();
  if (t<16){ int ky=t>>2, kx=t&3;
    float r = q2r[(ky<<3)+kx]+q2r[((ky+4)<<3)+kx]+q2r[(ky<<3)+kx+4]+q2r[((ky+4)<<3)+kx+4];
    float ii= q2i[(ky<<3)+kx]+q2i[((ky+4)<<3)+kx]+q2i[(ky<<3)+kx+4]+q2i[((ky+4)<<3)+kx+4];
    q1r[t]=r; q1i[t]=ii; UR[4+t]=r; UI[4+t]=ii; }
  __syncthreads();
  if (t<4){ int ky=t>>1, kx=t&1;
    float r = q1r[(ky<<2)+kx]+q1r[((ky+2)<<2)+kx]+q1r[(ky<<2)+kx+2]+q1r[((ky+2)<<2)+kx+2];
    float ii= q1i[(ky<<2)+kx]+q1i[((ky+2)<<2)+kx]+q1i[(ky<<2)+kx+2]+q1i[((ky+2)<<2)+kx+2];
    UR[t]=r; UI[t]=ii; }
}

// hot kernel v6: 6-d tiles, LDS-partials phase 1 (no shuffles), float4 La reads,
// U staged in LDS, level-4 split.  LDS = 9232 floats = 36.1 KB -> 4 blocks/CU
__global__ void __launch_bounds__(256) k_fold(float* __restrict__ ws){
  __shared__ float smem[9232];
  float* pre   = smem;          // 6x340
  float* pim   = smem + 2040;   // 6x340
  float* partr = smem + 4080;   // 6x256 (later: staged U re)
  float* parti = smem + 5616;   // 6x256 (later: staged U im)
  float* sLa   = smem + 7152;   // 6x284 (chain buffers overlay after phase 1)
  float* c64r  = smem + 7152;   // 384
  float* c64i  = smem + 7536;   // 384
  float* c16r  = smem + 7920;   // 96
  float* c16i  = smem + 8016;   // 96
  float* c4r   = smem + 8112;   // 24
  float* c4i   = smem + 8136;   // 24
  float* lamf  = smem + 8856;   // 340
  float* ssla  = smem + 9196;   // 36

  int t = threadIdx.x, bid = blockIdx.x;
  // m-major order: same-m blocks adjacent for LaT L2 reuse across batches
  int m    = bid / (NB*48);
  int rem  = bid % (NB*48);
  int b    = rem / 48;
  int tile = rem % 48;
  int lo = t_lo[tile], d0 = t_d0[tile], nd = t_nd[tile];
  int ho = g_hL[lo];
  int nbins = ho*ho;
  const float* zreb = ws + OFF_ZRE + b*12288;
  const float* zimb = ws + OFF_ZIM + b*12288;
  const float* latm = ws + OFF_LAT + (size_t)m*CTOT*CTOT;

  for (int i=t;i<340;i+=256) lamf[i] = ws[OFF_LAMF + m*340 + i];
  for (int i=t;i<nd*282;i+=256){ int d=i/282, c=i-d*282; sLa[d*284+c] = latm[(size_t)(d0+d)*CTOT + c]; }
  if (t<nd*6){ int d=t/6, c=t-d*6; ssla[t] = latm[(size_t)(d0+d)*CTOT + 276 + c]; }

  // task mapping (R4 style): t<64: level0 (16 chunks x 4 k); t<128: level1 (4 x 16); else level2 (2 x 64)
  int lA, kkA, c0A, nA;
  if (t<64){ lA=0; kkA=t&3; c0A=(t>>2)*12; nA=4; }
  else if (t<128){ int i=t-64; lA=1; kkA=i&15; c0A=(i>>4)*12; nA=16; }
  else { int i=t-128; lA=2; kkA=i&63; c0A=(i>>6)*12; nA=64; }
  float zAr[12], zAi[12], zBr[12], zBi[12];
  {
    const float* zr = zreb + g_zo[lA] + kkA;
    const float* zi = zimb + g_zo[lA] + kkA;
    #pragma unroll
    for (int c=0;c<12;c++){ zAr[c]=zr[(c0A+c)*nA]; zAi[c]=zi[(c0A+c)*nA]; }
    const float* zr3 = zreb + 3072 + t;
    const float* zi3 = zimb + 3072 + t;
    #pragma unroll
    for (int c=0;c<12;c++){ zBr[c]=zr3[c*256]; zBi[c]=zi3[c*256]; }
  }
  __syncthreads();

  // phase 1: per-d partials; La via ds_read_b128 (offsets are 16B-aligned)
  int offA = g_coff[lA] + c0A;
  for (int d=0; d<nd; d++){
    const float4* laA = (const float4*)(sLa + d*284 + offA);
    const float4* laB = (const float4*)(sLa + d*284 + 264);
    float4 a0=laA[0], a1=laA[1], a2=laA[2];
    float4 b0=laB[0], b1=laB[1], b2=laB[2];
    float av[12] = {a0.x,a0.y,a0.z,a0.w, a1.x,a1.y,a1.z,a1.w, a2.x,a2.y,a2.z,a2.w};
    float bv[12] = {b0.x,b0.y,b0.z,b0.w, b1.x,b1.y,b1.z,b1.w, b2.x,b2.y,b2.z,b2.w};
    float prA=0.f, piA=0.f, prB=0.f, piB=0.f;
    #pragma unroll
    for (int c=0;c<12;c++){ prA+=av[c]*zAr[c]; piA+=av[c]*zAi[c]; }
    #pragma unroll
    for (int c=0;c<12;c++){ prB+=bv[c]*zBr[c]; piB+=bv[c]*zBi[c]; }
    partr[(d<<8)+t]=prA; parti[(d<<8)+t]=piA;
    pre[d*340+84+t]=prB; pim[d*340+84+t]=piB;
  }
  __syncthreads();

  // reduce levels 0..2 partials into pre[0..84)
  for (int idx=t; idx<nd*84; idx+=256){
    int d=idx/84, s=idx-d*84;
    int base=d<<8;
    float r=0.f, ii=0.f;
    if (s<4){ for (int ch=0;ch<16;ch++){ int p=base+((ch<<2)|s); r+=partr[p]; ii+=parti[p]; } }
    else if (s<20){ int kk=s-4; for (int ch=0;ch<4;ch++){ int p=base+64+((ch<<4)|kk); r+=partr[p]; ii+=parti[p]; } }
    else { int kk=s-20; for (int ch=0;ch<2;ch++){ int p=base+128+((ch<<6)|kk); r+=partr[p]; ii+=parti[p]; } }
    pre[d*340+s]=r; pim[d*340+s]=ii;
  }
  __syncthreads();

  float sc = (float)ho/1024.f;
  if (lo==4){
    int dlb = d0 - 276;
    const float* lamA = ws + OFF_LAM + (m<<10);
    float* vRb = ws + OFF_VRE + (size_t)(b*NM+m)*12288 + 6144 + (dlb<<10);
    float* vIb = ws + OFF_VIM + (size_t)(b*NM+m)*12288 + 6144 + (dlb<<10);
    const float* z4r = zreb + 6144;
    const float* z4i = zimb + 6144;
    for (int q=t; q<1024; q+=256){
      int ky=q>>5, kx=q&31;
      int a0=((ky&1)<<1)|(kx&1);
      int a1=4+(((ky&3)<<2)|(kx&3));
      int a2=20+(((ky&7)<<3)|(kx&7));
      int a3=84+(((ky&15)<<4)|(kx&15));
      float zr_[6], zi_[6];
      #pragma unroll
      for (int c=0;c<6;c++){ zr_[c]=z4r[(c<<10)+q]; zi_[c]=z4i[(c<<10)+q]; }
      float lm = lamA[q]*sc;
      for (int d=0; d<nd; d++){
        const float* pd = pre + d*340; const float* qd = pim + d*340;
        float Br = pd[a0]+pd[a1]+pd[a2]+pd[a3];
        float Bi = qd[a0]+qd[a1]+qd[a2]+qd[a3];
        #pragma unroll
        for (int c=0;c<6;c++){ float a=ssla[d*6+c]; Br+=a*zr_[c]; Bi+=a*zi_[c]; }
        vRb[(d<<10)+q] = -lm*Bi;
        vIb[(d<<10)+q] =  lm*Br;
      }
    }
    return;
  }

  // chain c64 (direct from pre) + U staging into freed partr/parti
  if (lo<3){
    for (int idx=t; idx<nd*64; idx+=256){
      int d=idx>>6, k2=idx&63, ky=k2>>3, kx=k2&7;
      const float* pd = pre + d*340 + 84; const float* qd = pim + d*340 + 84;
      float r=0.f, ii=0.f;
      #pragma unroll
      for (int jy=0;jy<2;jy++)
        #pragma unroll
        for (int jx=0;jx<2;jx++){
          int a = ((ky+8*jy)<<4) | (kx+8*jx);
          float f = lamf[84+a];
          r += f*pd[a]; ii += f*qd[a];
        }
      if (lo<2){ float f=lamf[20+k2]; r+=f*pre[d*340+20+k2]; ii+=f*pim[d*340+20+k2]; }
      c64r[idx]=r; c64i[idx]=ii;
    }
  }
  {
    const float* URg = ws + OFF_UR + (size_t)((b*NM+m)*6)*340 + g_po[lo];
    const float* UIg = ws + OFF_UI + (size_t)((b*NM+m)*6)*340 + g_po[lo];
    for (int idx=t; idx<6*nbins; idx+=256){
      int c=idx/nbins, bin=idx-c*nbins;
      partr[idx]=URg[c*340+bin];
      parti[idx]=UIg[c*340+bin];
    }
  }
  __syncthreads();
  if (lo<2){
    for (int idx=t; idx<nd*16; idx+=256){
      int d=idx>>4, k2=idx&15, ky=k2>>2, kx=k2&3, base=d<<6;
      float r = c64r[base+(ky<<3)+kx]+c64r[base+((ky+4)<<3)+kx]+c64r[base+(ky<<3)+kx+4]+c64r[base+((ky+4)<<3)+kx+4];
      float ii= c64i[base+(ky<<3)+kx]+c64i[base+((ky+4)<<3)+kx]+c64i[base+(ky<<3)+kx+4]+c64i[base+((ky+4)<<3)+kx+4];
      if (lo<1){ float f=lamf[4+k2]; r+=f*pre[d*340+4+k2]; ii+=f*pim[d*340+4+k2]; }
      c16r[idx]=r; c16i[idx]=ii;
    }
  }
  __syncthreads();
  if (lo==0 && t<nd*4){
    int d=t>>2, k2=t&3, ky=k2>>1, kx=k2&1, base=d<<4;
    c4r[t]=c16r[base+(ky<<2)+kx]+c16r[base+((ky+2)<<2)+kx]+c16r[base+(ky<<2)+kx+2]+c16r[base+((ky+2)<<2)+kx+2];
    c4i[t]=c16i[base+(ky<<2)+kx]+c16i[base+((ky+2)<<2)+kx]+c16i[base+(ky<<2)+kx+2]+c16i[base+((ky+2)<<2)+kx+2];
  }
  __syncthreads();

  int dlb = d0 - g_coff[lo];
  float* vRb = ws + OFF_VRE + (size_t)(b*NM+m)*12288 + g_zo[lo];
  float* vIb = ws + OFF_VIM + (size_t)(b*NM+m)*12288 + g_zo[lo];
  for (int idx=t; idx<nd*nbins; idx+=256){
    int d=idx/nbins, bin=idx-d*nbins;
    int ky=bin/ho, kx=bin-ky*ho;
    const float* pd = pre + d*340; const float* qd = pim + d*340;
    float Br = pd[((ky&1)<<1)|(kx&1)], Bi = qd[((ky&1)<<1)|(kx&1)];
    if (lo>=1){ int ix=4+(((ky&3)<<2)|(kx&3)); Br+=pd[ix]; Bi+=qd[ix]; }
    if (lo>=2){ int ix=20+(((ky&7)<<3)|(kx&7)); Br+=pd[ix]; Bi+=qd[ix]; }
    if (lo>=3){ int ix=84+(((ky&15)<<4)|(kx&15)); Br+=pd[ix]; Bi+=qd[ix]; }
    float lf = lamf[g_po[lo]+bin];
    float Vr = lf*Br, Vi = lf*Bi;
    if (lo==2){ Vr+=c64r[(d<<6)+bin]; Vi+=c64i[(d<<6)+bin]; }
    else if (lo==1){ Vr+=c16r[(d<<4)+bin]; Vi+=c16i[(d<<4)+bin]; }
    else if (lo==0){ Vr+=c4r[(d<<2)+bin]; Vi+=c4i[(d<<2)+bin]; }
    #pragma unroll
    for (int c=0;c<6;c++){ float a=ssla[d*6+c]; Vr+=a*partr[c*nbins+bin]; Vi+=a*parti[c*nbins+bin]; }
    int ob = (dlb+d)*nbins + bin;
    vRb[ob] = -sc*Vi;
    vIb[ob] =  sc*Vr;
  }
}

// S_zz gram + S_zw: register-tiled (4 outputs/thread), float4 LDS reads
__global__ void __launch_bounds__(256) k_gram(float* __restrict__ ws){
  __shared__ float tile[32*260];
  __shared__ float wv[256];
  int t = threadIdx.x;
  int bid = blockIdx.x;
  int b = bid / 96, ch = bid % 96;
  int half = ch / 48;
  int k0 = (ch % 48) * 256;
  const float* V = ws + (half?OFF_VIM:OFF_VRE);
  const float* W = ws + (half?OFF_WIM:OFF_WRE) + b*12288 + k0;
  for (int i=t;i<32*256;i+=256){
    int r=i>>8, c=i&255;
    tile[r*260+c] = V[(size_t)(b*NM+r)*12288 + k0 + c];
  }
  wv[t] = W[t];
  __syncthreads();
  const float4* tf = (const float4*)tile;
  int n0 = t>>5, mm = t&31;
  float acc0=0.f, acc1=0.f, acc2=0.f, acc3=0.f;
  const float4* rm = tf + mm*65;
  const float4* r0 = tf + n0*65;
  const float4* r1 = tf + (n0+8)*65;
  const float4* r2 = tf + (n0+16)*65;
  const float4* r3 = tf + (n0+24)*65;
  for (int k4=0;k4<64;k4++){
    float4 vm = rm[k4];
    float4 v0 = r0[k4];
    float4 v1 = r1[k4];
    float4 v2 = r2[k4];
    float4 v3 = r3[k4];
    acc0 += v0.x*vm.x + v0.y*vm.y + v0.z*vm.z + v0.w*vm.w;
    acc1 += v1.x*vm.x + v1.y*vm.y + v1.z*vm.z + v1.w*vm.w;
    acc2 += v2.x*vm.x + v2.y*vm.y + v2.z*vm.z + v2.w*vm.w;
    acc3 += v3.x*vm.x + v3.y*vm.y + v3.z*vm.z + v3.w*vm.w;
  }
  float* szz = ws + OFF_SZZ + (b<<10);
  atomicAdd(&szz[(n0<<5) + mm], acc0);
  atomicAdd(&szz[((n0+8)<<5) + mm], acc1);
  atomicAdd(&szz[((n0+16)<<5) + mm], acc2);
  atomicAdd(&szz[((n0+24)<<5) + mm], acc3);
  if (t < 32){
    const float4* rn = tf + t*65;
    const float4* wf = (const float4*)wv;
    float acc=0.f;
    for (int k4=0;k4<64;k4++){
      float4 a = rn[k4]; float4 wq = wf[k4];
      acc += a.x*wq.x + a.y*wq.y + a.z*wq.z + a.w*wq.w;
    }
    atomicAdd(&ws[OFF_SZW + (b<<5) + t], acc);
  }
}

// var, normalize, Cholesky 32x32 in LDS, logdet, trace, output
__global__ void k_final(float* __restrict__ ws, float* __restrict__ out){
  __shared__ float A[32][33];
  __shared__ float svar;
  int b = blockIdx.x, t = threadIdx.x;
  const float* szz = ws + OFF_SZZ + (b<<10);
  if (t==0){
    float s=0.f;
    for (int i=0;i<32;i++) s += szz[i*33];
    svar = fmaxf(s/32.0f, 1e-6f);
  }
  __syncthreads();
  float var = svar;
  for (int i=t;i<1024;i+=64){
    int r=i>>5, c=i&31;
    A[r][c] = szz[i]/var + ((r==c)?EPSV:0.0f);
  }
  __syncthreads();
  for (int j=0;j<32;j++){
    if (t==0) A[j][j] = sqrtf(A[j][j]);
    __syncthreads();
    if (t>j && t<32) A[t][j] /= A[j][j];
    __syncthreads();
    if (t>j && t<32){
      float lij = A[t][j];
      for (int k=j+1;k<=t;k++) A[t][k] -= lij*A[k][j];
    }
    __syncthreads();
  }
  if (t==0){
    float logdet=0.f;
    for (int j=0;j<32;j++) logdet += logf(A[j][j]);
    logdet *= 2.0f;
    const float* szw = ws + OFF_SZW + (b<<5);
    float s2=0.f;
    for (int n=0;n<32;n++) s2 += szw[n]*szw[n];
    float trace = EPSV*ws[OFF_SWW + b] + s2/var;
    out[b] = 0.5f*(logdet - trace);
  }
}

extern "C" void kernel_launch(void* const* d_in, const int* in_sizes, int n_in,
                              void* d_out, int out_size, void* d_ws, size_t ws_size,
                              hipStream_t stream){
  // setup_inputs() dict order is INTERLEAVED: z0,w0,z1,w1,z2,w2,z3,w3,z4,w4,L,lam
  const float* z0 = (const float*)d_in[0];
  const float* w0 = (const float*)d_in[1];
  const float* z1 = (const float*)d_in[2];
  const float* w1 = (const float*)d_in[3];
  const float* z2 = (const float*)d_in[4];
  const float* w2 = (const float*)d_in[5];
  const float* z3 = (const float*)d_in[6];
  const float* w3 = (const float*)d_in[7];
  const float* z4 = (const float*)d_in[8];
  const float* w4 = (const float*)d_in[9];
  const float* L   = (const float*)d_in[10];
  const float* lam = (const float*)d_in[11];
  float* ws = (float*)d_ws;
  float* out = (float*)d_out;

  k_pre<<<PRE_ZERO, 256, 0, stream>>>(z0,z1,z2,z3,z4,w0,w1,w2,w3,w4, L, lam, ws);
  k_u<<<NB*NM*6, 256, 0, stream>>>(ws);
  k_fold<<<NB*NM*48, 256, 0, stream>>>(ws);
  k_gram<<<NB*96, 256, 0, stream>>>(ws);
  k_final<<<NB, 64, 0, stream>>>(ws, out);
}